// Round 18
// baseline (267.191 us; speedup 1.0000x reference)
//
#include <hip/hip_runtime.h>

#define N_NODES 20000
#define N_EDGES 320000
#define INV_SQRT3 0.5773502691896258f

typedef unsigned short u16;
typedef unsigned int u32;
typedef __attribute__((ext_vector_type(8))) short short8;
typedef __attribute__((ext_vector_type(8))) _Float16 half8;
typedef __attribute__((ext_vector_type(2))) __fp16 fp16x2;
typedef __attribute__((ext_vector_type(4))) float f32x4;
typedef __attribute__((ext_vector_type(4))) u32 u32x4v;

// ---- workspace layout (bytes), ws = 256 MiB ----
static const size_t OFF_NSBF = 0;            // N*64 bf16
static const size_t OFF_SV   = 2560000;      // N*64 * 4 fp16 (8B/ch)
static const size_t OFF_MG   = 23040000;     // N*512 f32
static const size_t OFF_TW   = 64000000;     // E*256 fp16, channel-major [c*4+q]
static const size_t OFF_W1F  = 227840000;    // 20480
static const size_t OFF_W2F  = 227860480;    // 8192
static const size_t OFF_W3F  = 227868672;    // 32768
static const size_t OFF_WNF  = 227901440;    // 49152
static const size_t OFF_CNT  = 227950592;    // 80000
static const size_t OFF_OFFS = 228030592;    // 80016
static const size_t OFF_CUR  = 228110608;    // 80000 (cursor only)
static const size_t OFF_SS   = 229470608;    // 1,280,000
static const size_t OFF_RS   = 230750608;    // 1,280,000
static const size_t OFF_EA   = 232030608;    // E*16B easort
static const size_t OFF_EF   = 237150608;    // E*16B efsort (8 bf16)
static const size_t OFF_LEN  = 242270608;    // E*2B lsort
static const size_t OFF_WSF  = 243550608;    // 64KB Ws/Wv hi-lo frags -> ends 243,616,144

static __device__ __forceinline__ u16 f2bf(float x) {
    union { float f; u32 u; } c; c.f = x;
    u32 u = c.u + 0x7fffu + ((c.u >> 16) & 1u);
    return (u16)(u >> 16);
}
static __device__ __forceinline__ float bf2f(u16 b) {
    union { u32 u; float f; } c; c.u = (u32)b << 16; return c.f;
}
static __device__ __forceinline__ u16 f2h(float x) {
    union { _Float16 h; u16 u; } c; c.h = (_Float16)x; return c.u;
}
static __device__ __forceinline__ float h2f(u32 b) {
    union { u16 u; _Float16 h; } c; c.u = (u16)b; return (float)c.h;
}
static __device__ __forceinline__ u32 pkh(float a, float b) {
    union { fp16x2 h; u32 u; } c;
    c.h = __builtin_amdgcn_cvt_pkrtz(a, b);
    return c.u;
}
static __device__ __forceinline__ f32x4 mfma16(short8 a, short8 b, f32x4 c) {
    return __builtin_amdgcn_mfma_f32_16x16x32_bf16(a, b, c, 0, 0, 0);
}
static __device__ __forceinline__ f32x4 mfma16h(half8 a, half8 b, f32x4 c) {
    return __builtin_amdgcn_mfma_f32_16x16x32_f16(a, b, c, 0, 0, 0);
}
static __device__ __forceinline__ float silu(float x) {
    return x / (1.0f + __expf(-x));
}
template <typename T>
static __device__ __forceinline__ T ntload(const T* p) { return __builtin_nontemporal_load(p); }
template <typename T>
static __device__ __forceinline__ void ntstore(T* p, T v) { __builtin_nontemporal_store(v, p); }

// ---- merged weight prep: W1/W2/W3 frags + Wsc/Wup frags + Ws/Wv hi-lo frags ----
__global__ void prep_all_kernel(const float* __restrict__ W1, const float* __restrict__ W2,
                                const float* __restrict__ W3,
                                const float* __restrict__ Wsc, const float* __restrict__ Wup0,
                                const float* __restrict__ Wup1,
                                const float* __restrict__ Ws, const float* __restrict__ Wv,
                                u16* __restrict__ W1f, u16* __restrict__ W2f,
                                u16* __restrict__ W3f, u16* __restrict__ WNF,
                                u16* __restrict__ WSF) {
    int t = blockIdx.x * 256 + threadIdx.x;
    if (t < 3840) {
        int l = t & 63, grp = t >> 6;
        int hi = l >> 4, lo = l & 15;
        if (grp < 20) {
            int kk = grp >> 2, jt = grp & 3;
#pragma unroll
            for (int e2 = 0; e2 < 8; e2++) {
                int k = kk * 32 + hi * 8 + e2, j = jt * 16 + lo;
                W1f[(size_t)(grp * 64 + l) * 8 + e2] = (k < 137) ? f2bf(W1[k * 64 + j]) : (u16)0;
            }
        } else if (grp < 28) {
            int g = grp - 20; int kk = g >> 2, jt = g & 3;
#pragma unroll
            for (int e2 = 0; e2 < 8; e2++) {
                int k = kk * 32 + hi * 8 + e2, j = jt * 16 + lo;
                int kp = ((k & 3) << 4) + (k >> 2);
                W2f[(size_t)(g * 64 + l) * 8 + e2] = f2h(W2[kp * 64 + j]);
            }
        } else {
            int g = grp - 28; int kk = g >> 4, jt = g & 15;
#pragma unroll
            for (int e2 = 0; e2 < 8; e2++) {
                int k = kk * 32 + hi * 8 + e2, j = jt * 16 + lo;
                int kp = ((k & 3) << 4) + (k >> 2);
                W3f[(size_t)(g * 64 + l) * 8 + e2] = f2h(W3[kp * 256 + j]);
            }
        }
    } else if (t < 5376) {
        int tt = t - 3840;
        int mat = tt >> 9;
        int rem = tt & 511;
        int g = rem >> 6, l = rem & 63;
        int kk = g >> 2, jt = g & 3, hi = l >> 4, lo = l & 15;
        const float* W = (mat == 0) ? Wsc : (mat == 1) ? Wup0 : Wup1;
        u16* dh = WNF + (size_t)mat * 8192 + (size_t)(g * 64 + l) * 8;
        u16* dl = dh + 4096;
#pragma unroll
        for (int e2 = 0; e2 < 8; e2++) {
            int k = kk * 32 + hi * 8 + e2, d = jt * 16 + lo;
            float w = W[k * 64 + d];
            u16 h = f2bf(w);
            dh[e2] = h;
            dl[e2] = f2bf(w - bf2f(h));
        }
    } else if (t < 7424) {
        int tt = t - 5376;
        int l = tt & 63, grp = tt >> 6;
        int wsel = grp >> 4;
        int g = grp & 15;
        int kk = g >> 2, jt = g & 3;
        int hi = l >> 4, lo = l & 15;
        const float* W = wsel ? Wv : Ws;
        u16* dh = WSF + (size_t)wsel * 16384;
        u16* dl = dh + 8192;
        size_t base = (size_t)(g * 64 + l) * 8;
#pragma unroll
        for (int e2 = 0; e2 < 8; e2++) {
            int k = kk * 32 + hi * 8 + e2, d = jt * 16 + lo;
            float w = W[k * 64 + d];
            u16 h = f2bf(w);
            float r = w - bf2f(h);
            dh[base + e2] = h;
            dl[base + e2] = f2bf(r);
        }
    }
}

// ---- node precompute: MFMA, hi/lo split A; sv output packed fp16 ----
__global__ __launch_bounds__(256) void node_prep_kernel(
    const float* __restrict__ node_feats, const u16* __restrict__ WNF,
    u16* __restrict__ ns_bf, u16* __restrict__ svh) {
    const int tid = threadIdx.x;
    const int lane = tid & 63;
    const int w = tid >> 6;
    const int lo16 = lane & 15;
    const int hi = lane >> 4;
    const int nb = blockIdx.x * 64 + w * 16;

    int an = nb + lo16; if (an > N_NODES - 1) an = N_NODES - 1;
    const float* arow = node_feats + (size_t)an * 256;

    const short8* B = (const short8*)WNF;

    f32x4 acc_ns[4], acc_su[4], acc_v[3][4];
#pragma unroll
    for (int jt = 0; jt < 4; jt++) {
        acc_ns[jt] = (f32x4)(0.0f);
        acc_su[jt] = (f32x4)(0.0f);
#pragma unroll
        for (int i = 0; i < 3; i++) acc_v[i][jt] = (f32x4)(0.0f);
    }

#pragma unroll
    for (int kk = 0; kk < 2; kk++) {
        short8 sh, sl;
        {
            const float* sp = arow + kk * 32 + hi * 8;
            f32x4 x0 = *(const f32x4*)sp;
            f32x4 x1 = *(const f32x4*)(sp + 4);
#pragma unroll
            for (int j = 0; j < 4; j++) {
                u16 h0 = f2bf(x0[j]);
                sh[j] = (short)h0;
                sl[j] = (short)f2bf(x0[j] - bf2f(h0));
                u16 h1 = f2bf(x1[j]);
                sh[4 + j] = (short)h1;
                sl[4 + j] = (short)f2bf(x1[j] - bf2f(h1));
            }
        }
        short8 vh[3], vl[3];
#pragma unroll
        for (int i = 0; i < 3; i++) {
            const float* vp = arow + 64 + i + 3 * (kk * 32 + hi * 8);
#pragma unroll
            for (int e = 0; e < 8; e++) {
                float x = vp[e * 3];
                u16 hb = f2bf(x);
                vh[i][e] = (short)hb;
                vl[i][e] = (short)f2bf(x - bf2f(hb));
            }
        }
#pragma unroll
        for (int jt = 0; jt < 4; jt++) {
            int fi = (kk * 4 + jt) * 64 + lane;
            short8 bh = B[fi], bl = B[512 + fi];
            acc_ns[jt] = mfma16(sh, bh, acc_ns[jt]);
            acc_ns[jt] = mfma16(sl, bh, acc_ns[jt]);
            acc_ns[jt] = mfma16(sh, bl, acc_ns[jt]);
            bh = B[1024 + fi]; bl = B[1536 + fi];
            acc_su[jt] = mfma16(sh, bh, acc_su[jt]);
            acc_su[jt] = mfma16(sl, bh, acc_su[jt]);
            acc_su[jt] = mfma16(sh, bl, acc_su[jt]);
            bh = B[2048 + fi]; bl = B[2560 + fi];
#pragma unroll
            for (int i = 0; i < 3; i++) {
                acc_v[i][jt] = mfma16(vh[i], bh, acc_v[i][jt]);
                acc_v[i][jt] = mfma16(vl[i], bh, acc_v[i][jt]);
                acc_v[i][jt] = mfma16(vh[i], bl, acc_v[i][jt]);
            }
        }
    }

#pragma unroll
    for (int r = 0; r < 4; r++) {
        int n = nb + hi * 4 + r;
        if (n < N_NODES) {
#pragma unroll
            for (int jt = 0; jt < 4; jt++) {
                int d = jt * 16 + lo16;
                ns_bf[(size_t)n * 64 + d] = f2bf(acc_ns[jt][r]);
                uint2 o;
                o.x = pkh(acc_su[jt][r], acc_v[0][jt][r]);
                o.y = pkh(acc_v[1][jt][r], acc_v[2][jt][r]);
                *(uint2*)&svh[((size_t)n * 64 + d) * 4] = o;
            }
        }
    }
}

// ---- counting sort by rcv ----
__global__ void hist_kernel(const int* __restrict__ ei, int* __restrict__ cnt) {
    int e = blockIdx.x * 256 + threadIdx.x;
    if (e < N_EDGES) atomicAdd(&cnt[ei[N_EDGES + e]], 1);
}

__global__ void scan_kernel(const int* __restrict__ cnt, int* __restrict__ offs,
                            int* __restrict__ cursor) {
    __shared__ int buf[1024];
    int t = threadIdx.x;
    int base = t * 20;
    int loc[20];
    int tot = 0;
    int v20[20];
    if (base < N_NODES) {
#pragma unroll
        for (int q = 0; q < 5; q++) {
            int4 vv = *(const int4*)&cnt[base + q * 4];
            v20[q * 4 + 0] = vv.x; v20[q * 4 + 1] = vv.y;
            v20[q * 4 + 2] = vv.z; v20[q * 4 + 3] = vv.w;
        }
    } else {
#pragma unroll
        for (int i = 0; i < 20; i++) v20[i] = 0;
    }
#pragma unroll
    for (int i = 0; i < 20; i++) { loc[i] = tot; tot += v20[i]; }
    buf[t] = tot;
    __syncthreads();
    for (int d = 1; d < 1024; d <<= 1) {
        int add = (t >= d) ? buf[t - d] : 0;
        __syncthreads();
        buf[t] += add;
        __syncthreads();
    }
    int ebase = buf[t] - tot;
#pragma unroll
    for (int i = 0; i < 20; i++) {
        int idx = base + i;
        if (idx < N_NODES) { int o = ebase + loc[i]; offs[idx] = o; cursor[idx] = o; }
    }
    if (t == 1023) offs[N_NODES] = buf[1023];
}

// ---- scatter: sort + pre-gather edge payloads into sorted order ----
__global__ void scatter_kernel(const int* __restrict__ ei, const float* __restrict__ edge_attrs,
                               const float* __restrict__ edge_feats, const float* __restrict__ lengths,
                               int* __restrict__ cursor,
                               int* __restrict__ ssort, int* __restrict__ rsort,
                               float* __restrict__ easort, u16* __restrict__ efsort,
                               u16* __restrict__ lsort) {
    int e = blockIdx.x * 256 + threadIdx.x;
    if (e < N_EDGES) {
        int sn = ei[e];
        int rc = ei[N_EDGES + e];
        float4 ea = *(const float4*)(edge_attrs + (size_t)e * 4);
        float4 f0 = *(const float4*)(edge_feats + (size_t)e * 8);
        float4 f1 = *(const float4*)(edge_feats + (size_t)e * 8 + 4);
        float len = lengths[e];
        uint4 pk;
        pk.x = (u32)f2bf(f0.x) | ((u32)f2bf(f0.y) << 16);
        pk.y = (u32)f2bf(f0.z) | ((u32)f2bf(f0.w) << 16);
        pk.z = (u32)f2bf(f1.x) | ((u32)f2bf(f1.y) << 16);
        pk.w = (u32)f2bf(f1.z) | ((u32)f2bf(f1.w) << 16);
        int pos = atomicAdd(&cursor[rc], 1);
        ssort[pos] = sn;
        rsort[pos] = rc;
        *(float4*)(easort + (size_t)pos * 4) = ea;
        *(uint4*)(efsort + (size_t)pos * 8) = pk;
        lsort[pos] = f2bf(len);
    }
}

// ---- K3: edge MLP. Single LDS buffer, STRICTLY row-private per wave:
//      staging cols 0..167; after L1 reads, h1 -> cols 72..136; after L2 reads of h1,
//      h2 -> cols 0..64. All writes follow same-wave in-order DS reads of that row;
//      rows [16w,16w+16) owned by wave w -> no races, NO barriers. 21.5KB LDS -> 7 blocks/CU. ----
__global__ __launch_bounds__(256, 7) void mlp_kernel(
    const u16* __restrict__ ns_bf,
    const u16* __restrict__ W1f, const u16* __restrict__ W2f, const u16* __restrict__ W3f,
    const float* __restrict__ b1, const float* __restrict__ b2,
    const int* __restrict__ ssort, const int* __restrict__ rsort,
    const u16* __restrict__ efsort, const u16* __restrict__ lsort,
    u16* __restrict__ twg) {

    __shared__ u16 mlpbuf[64][168];

    const int tid = threadIdx.x;
    const int l = tid & 63;
    const int lo16 = l & 15;
    const int hi = l >> 4;
    const int w = tid >> 6;
    const int erow = (w << 4) | lo16;
    const int koff = hi * 8;
    const int drow = (w << 4) + hi * 4;

    // XCD-aware swizzle: grid 5000 = 8 XCDs x 625 contiguous blocks
    const int nwg = N_EDGES / 64;
    const int cpx = nwg / 8;
    const int bid = (int)blockIdx.x;
    const int swz = (bid % 8) * cpx + bid / 8;
    const int p0 = swz * 64;

    const short8* w1frag = (const short8*)W1f;
    const half8* w2frag = (const half8*)W2f;
    const half8* w3frag = (const half8*)W3f;

    float bb1[4], bb2[4];
#pragma unroll
    for (int jt = 0; jt < 4; jt++) { bb1[jt] = b1[jt * 16 + lo16]; bb2[jt] = b2[jt * 16 + lo16]; }

    // zero pad region k=136..167 (wave-private rows)
    {
        int rr = tid >> 2, pp = tid & 3;
        uint4 z = {0, 0, 0, 0};
        *(uint4*)&mlpbuf[rr][136 + pp * 8] = z;
    }

    // stage gathered edge inputs (wave-private rows)
    {
        int es = tid >> 2, part = tid & 3;
        int sn = ssort[p0 + es];
        int rc = rsort[p0 + es];
        const uint4* ps = (const uint4*)(ns_bf + (size_t)sn * 64 + part * 16);
        uint4 s0 = ps[0], s1 = ps[1];
        *(uint4*)&mlpbuf[es][part * 16] = s0;
        *(uint4*)&mlpbuf[es][part * 16 + 8] = s1;
        const uint4* pr = (const uint4*)(ns_bf + (size_t)rc * 64 + part * 16);
        uint4 r0v = pr[0], r1v = pr[1];
        *(uint4*)&mlpbuf[es][64 + part * 16] = r0v;
        *(uint4*)&mlpbuf[es][64 + part * 16 + 8] = r1v;
        if (part == 0) {
            uint4 pk = *(const uint4*)(efsort + (size_t)(p0 + es) * 8);
            *(uint4*)&mlpbuf[es][128] = pk;
            mlpbuf[es][136] = lsort[p0 + es];
        }
    }
    // no barrier: rows are wave-private; per-wave in-order DS execution suffices

    // layer 1: (64x160) @ (160x64), bf16
    f32x4 a1c[4];
#pragma unroll
    for (int jt = 0; jt < 4; jt++) a1c[jt] = (f32x4)(0.0f);
    __builtin_amdgcn_s_setprio(1);
#pragma unroll
    for (int kk = 0; kk < 5; kk++) {
        short8 af = *(const short8*)&mlpbuf[erow][kk * 32 + koff];
        const short8* wb = w1frag + kk * 256 + l;
        a1c[0] = mfma16(af, wb[0],   a1c[0]);
        a1c[1] = mfma16(af, wb[64],  a1c[1]);
        a1c[2] = mfma16(af, wb[128], a1c[2]);
        a1c[3] = mfma16(af, wb[192], a1c[3]);
    }
    __builtin_amdgcn_s_setprio(0);
    // h1 -> cols 72..136 of own rows (L1 reads of these rows already done, in order)
#pragma unroll
    for (int r = 0; r < 4; r++) {
        uint2 pk;
        pk.x = pkh(silu(a1c[0][r] + bb1[0]), silu(a1c[1][r] + bb1[1]));
        pk.y = pkh(silu(a1c[2][r] + bb1[2]), silu(a1c[3][r] + bb1[3]));
        *(uint2*)&mlpbuf[drow + r][72 + lo16 * 4] = pk;
    }

    // layer 2: (64x64) @ (64x64), fp16 (permuted K); h1 at cols 72..136
    f32x4 a2c[4];
#pragma unroll
    for (int jt = 0; jt < 4; jt++) a2c[jt] = (f32x4)(0.0f);
    __builtin_amdgcn_s_setprio(1);
#pragma unroll
    for (int kk = 0; kk < 2; kk++) {
        half8 af = *(const half8*)&mlpbuf[erow][72 + kk * 32 + koff];
        const half8* wb = w2frag + kk * 256 + l;
        a2c[0] = mfma16h(af, wb[0],   a2c[0]);
        a2c[1] = mfma16h(af, wb[64],  a2c[1]);
        a2c[2] = mfma16h(af, wb[128], a2c[2]);
        a2c[3] = mfma16h(af, wb[192], a2c[3]);
    }
    __builtin_amdgcn_s_setprio(0);
    // h2 -> cols 0..64 of own rows (L2 reads done)
#pragma unroll
    for (int r = 0; r < 4; r++) {
        uint2 pk;
        pk.x = pkh(silu(a2c[0][r] + bb2[0]), silu(a2c[1][r] + bb2[1]));
        pk.y = pkh(silu(a2c[2][r] + bb2[2]), silu(a2c[3][r] + bb2[3]));
        *(uint2*)&mlpbuf[drow + r][lo16 * 4] = pk;
    }

    // layer 3: (64x64) @ (64x256), fp16 (permuted K); h2 at cols 0..64
    f32x4 tw[16];
#pragma unroll
    for (int jt = 0; jt < 16; jt++) tw[jt] = (f32x4)(0.0f);
    __builtin_amdgcn_s_setprio(1);
#pragma unroll
    for (int kk = 0; kk < 2; kk++) {
        half8 af = *(const half8*)&mlpbuf[erow][kk * 32 + koff];
        const half8* wb = w3frag + kk * 1024 + l;
#pragma unroll
        for (int jt = 0; jt < 16; jt++) tw[jt] = mfma16h(af, wb[jt * 64], tw[jt]);
    }
    __builtin_amdgcn_s_setprio(0);

    // store tw channel-major: tw[jt] -> q = jt>>2, c = (jt&3)*16+lo16; twg[e*256 + c*4 + q]
    int relrow = p0 + drow;
#pragma unroll
    for (int r = 0; r < 4; r++) {
        u16* dst = twg + (size_t)(relrow + r) * 256 + lo16 * 4;
#pragma unroll
        for (int jt4 = 0; jt4 < 4; jt4++) {
            uint2 pk;
            pk.x = pkh(tw[jt4][r],     tw[4 + jt4][r]);
            pk.y = pkh(tw[8 + jt4][r], tw[12 + jt4][r]);
            *(uint2*)(dst + jt4 * 64) = pk;
        }
    }
}

// ---- K4: one wave per node; tensor products + register segment-sum;
//      channel-major tw; XCD-swizzled blockIdx ----
__global__ __launch_bounds__(256, 4) void seg_kernel(
    const u16* __restrict__ svh, const float* __restrict__ easort,
    const int* __restrict__ ssort,
    const int* __restrict__ offs, const u16* __restrict__ twg,
    float* __restrict__ m_g) {
    const int lane = threadIdx.x & 63;
    const int wv = threadIdx.x >> 6;
    const int nwg = N_NODES / 4;
    const int cpx = nwg / 8;
    const int bid = (int)blockIdx.x;
    const int swz = (bid % 8) * cpx + bid / 8;
    const int n = swz * 4 + wv;
    const int c = lane;
    const int e0 = offs[n], e1 = offs[n + 1];
    float a_m0 = 0.f, a_m0b = 0.f;
    float a20 = 0.f, a21 = 0.f, a22 = 0.f, a30 = 0.f, a31 = 0.f, a32 = 0.f;
#pragma unroll 4
    for (int pos = e0; pos < e1; ++pos) {
        int sn = ssort[pos];
        uint2 tq = *(const uint2*)(twg + (size_t)pos * 256 + c * 4);
        f32x4 y4 = *(const f32x4*)(easort + (size_t)pos * 4);
        uint2 sp = *(const uint2*)&svh[((size_t)sn * 64 + c) * 4];
        float w0 = h2f(tq.x & 0xffffu);
        float w1 = h2f(tq.x >> 16);
        float w2 = h2f(tq.y & 0xffffu);
        float w3 = h2f(tq.y >> 16);
        float xs  = h2f(sp.x & 0xffffu);
        float xv0 = h2f(sp.x >> 16);
        float xv1 = h2f(sp.y & 0xffffu);
        float xv2 = h2f(sp.y >> 16);
        float y0 = y4.x, ya = y4.y, yb = y4.z, yc = y4.w;
        a_m0 = fmaf(xs * y0, w0, a_m0);
        float dv = xv0 * ya + xv1 * yb + xv2 * yc;
        a_m0b = fmaf(dv, w1, a_m0b);
        float sw2 = xs * w2;
        a20 = fmaf(sw2, ya, a20); a21 = fmaf(sw2, yb, a21); a22 = fmaf(sw2, yc, a22);
        float yw3 = y0 * w3;
        a30 = fmaf(xv0, yw3, a30); a31 = fmaf(xv1, yw3, a31); a32 = fmaf(xv2, yw3, a32);
    }
    float* mr = m_g + (size_t)n * 512;
    ntstore(mr + c,        a_m0);
    ntstore(mr + 64 + c,   a_m0b * INV_SQRT3);
    ntstore(mr + 128 + c,  a20);
    ntstore(mr + 192 + c,  a30);
    ntstore(mr + 256 + c,  a21);
    ntstore(mr + 320 + c,  a31);
    ntstore(mr + 384 + c,  a22);
    ntstore(mr + 448 + c,  a32);
}

// ---- K5: MFMA epilogue. 64 nodes/block, 4 waves, no LDS, no barriers. ----
__global__ __launch_bounds__(256, 2) void out_kernel(
    const float* __restrict__ m_g, const u16* __restrict__ WSF,
    float* __restrict__ out) {
    const int tid = threadIdx.x;
    const int lane = tid & 63;
    const int w = tid >> 6;
    const int lo16 = lane & 15;
    const int hi = lane >> 4;
    const int nb = blockIdx.x * 64 + w * 16;

    int arow_n = nb + lo16;
    if (arow_n > N_NODES - 1) arow_n = N_NODES - 1;
    const float* arow = m_g + (size_t)arow_n * 512 + hi * 8;

    const short8* bsh = (const short8*)WSF;
    const short8* bsl = (const short8*)(WSF + 8192);
    const short8* bvh = (const short8*)(WSF + 16384);
    const short8* bvl = (const short8*)(WSF + 24576);

    f32x4 acc[4][4];
#pragma unroll
    for (int q = 0; q < 4; q++)
#pragma unroll
        for (int jt = 0; jt < 4; jt++) acc[q][jt] = (f32x4)(0.0f);

#pragma unroll
    for (int kk = 0; kk < 4; kk++) {
        short8 ahi[4], alo[4];
#pragma unroll
        for (int q = 0; q < 4; q++) {
            const float* p = arow + q * 128 + kk * 32;
            f32x4 x0 = ntload((const f32x4*)p);
            f32x4 x1 = ntload((const f32x4*)(p + 4));
#pragma unroll
            for (int j = 0; j < 4; j++) {
                u16 h0 = f2bf(x0[j]);
                ahi[q][j] = (short)h0;
                alo[q][j] = (short)f2bf(x0[j] - bf2f(h0));
                u16 h1 = f2bf(x1[j]);
                ahi[q][4 + j] = (short)h1;
                alo[q][4 + j] = (short)f2bf(x1[j] - bf2f(h1));
            }
        }
#pragma unroll
        for (int jt = 0; jt < 4; jt++) {
            int bidx = (kk * 4 + jt) * 64 + lane;
            short8 wh_s = bsh[bidx];
            short8 wl_s = bsl[bidx];
            short8 wh_v = bvh[bidx];
            short8 wl_v = bvl[bidx];
            acc[0][jt] = mfma16(ahi[0], wh_s, acc[0][jt]);
            acc[0][jt] = mfma16(alo[0], wh_s, acc[0][jt]);
            acc[0][jt] = mfma16(ahi[0], wl_s, acc[0][jt]);
#pragma unroll
            for (int q = 1; q < 4; q++) {
                acc[q][jt] = mfma16(ahi[q], wh_v, acc[q][jt]);
                acc[q][jt] = mfma16(alo[q], wh_v, acc[q][jt]);
                acc[q][jt] = mfma16(ahi[q], wl_v, acc[q][jt]);
            }
        }
    }

#pragma unroll
    for (int r = 0; r < 4; r++) {
        int n = nb + hi * 4 + r;
        if (n < N_NODES) {
#pragma unroll
            for (int jt = 0; jt < 4; jt++) {
                int d = jt * 16 + lo16;
                f32x4 o;
                o.x = acc[0][jt][r] * 0.0625f;
                o.y = acc[1][jt][r] * 0.0625f;
                o.z = acc[2][jt][r] * 0.0625f;
                o.w = acc[3][jt][r] * 0.0625f;
                ntstore((f32x4*)(out + (size_t)n * 256 + d * 4), o);
            }
        }
    }
}

extern "C" void kernel_launch(void* const* d_in, const int* in_sizes, int n_in,
                              void* d_out, int out_size, void* d_ws, size_t ws_size,
                              hipStream_t stream) {
    (void)in_sizes; (void)n_in; (void)out_size; (void)ws_size;
    const float* node_feats = (const float*)d_in[0];
    const float* edge_attrs = (const float*)d_in[1];
    const float* edge_feats = (const float*)d_in[2];
    const float* lengths    = (const float*)d_in[3];
    const int*   edge_index = (const int*)d_in[4];
    const float* Wsc  = (const float*)d_in[5];
    const float* Wup0 = (const float*)d_in[6];
    const float* Wup1 = (const float*)d_in[7];
    const float* W1   = (const float*)d_in[8];
    const float* b1   = (const float*)d_in[9];
    const float* W2   = (const float*)d_in[10];
    const float* b2   = (const float*)d_in[11];
    const float* W3   = (const float*)d_in[12];
    const float* Ws   = (const float*)d_in[13];
    const float* Wv   = (const float*)d_in[14];

    char* ws = (char*)d_ws;
    u16*   ns_bf  = (u16*)(ws + OFF_NSBF);
    u16*   svh    = (u16*)(ws + OFF_SV);
    float* m_g    = (float*)(ws + OFF_MG);
    u16*   twg    = (u16*)(ws + OFF_TW);
    u16*   W1f    = (u16*)(ws + OFF_W1F);
    u16*   W2f    = (u16*)(ws + OFF_W2F);
    u16*   W3f    = (u16*)(ws + OFF_W3F);
    u16*   WNF    = (u16*)(ws + OFF_WNF);
    int*   cnt    = (int*)(ws + OFF_CNT);
    int*   offs   = (int*)(ws + OFF_OFFS);
    int*   cursor = (int*)(ws + OFF_CUR);
    u16*   WSF    = (u16*)(ws + OFF_WSF);
    int*   ssort  = (int*)(ws + OFF_SS);
    int*   rsort  = (int*)(ws + OFF_RS);
    float* easort = (float*)(ws + OFF_EA);
    u16*   efsort = (u16*)(ws + OFF_EF);
    u16*   lsort  = (u16*)(ws + OFF_LEN);
    float* out    = (float*)d_out;

    (void)hipMemsetAsync(cnt, 0, N_NODES * sizeof(int), stream);
    prep_all_kernel<<<29, 256, 0, stream>>>(W1, W2, W3, Wsc, Wup0, Wup1, Ws, Wv,
                                            W1f, W2f, W3f, WNF, WSF);
    node_prep_kernel<<<(N_NODES + 63) / 64, 256, 0, stream>>>(node_feats, WNF, ns_bf, svh);
    hist_kernel<<<N_EDGES / 256, 256, 0, stream>>>(edge_index, cnt);
    scan_kernel<<<1, 1024, 0, stream>>>(cnt, offs, cursor);
    scatter_kernel<<<N_EDGES / 256, 256, 0, stream>>>(edge_index, edge_attrs, edge_feats,
                                                      lengths, cursor,
                                                      ssort, rsort, easort, efsort, lsort);

    mlp_kernel<<<N_EDGES / 64, 256, 0, stream>>>(ns_bf, W1f, W2f, W3f, b1, b2,
                                                 ssort, rsort, efsort, lsort, twg);
    seg_kernel<<<N_NODES / 4, 256, 0, stream>>>(svh, easort, ssort,
                                                offs, twg, m_g);
    out_kernel<<<(N_NODES + 63) / 64, 256, 0, stream>>>(m_g, WSF, out);
}

// Round 19
// 231.029 us; speedup vs baseline: 1.1565x; 1.1565x over previous
//
#include <hip/hip_runtime.h>

#define N_NODES 20000
#define N_EDGES 320000
#define INV_SQRT3 0.5773502691896258f

typedef unsigned short u16;
typedef unsigned int u32;
typedef __attribute__((ext_vector_type(8))) short short8;
typedef __attribute__((ext_vector_type(8))) _Float16 half8;
typedef __attribute__((ext_vector_type(2))) __fp16 fp16x2;
typedef __attribute__((ext_vector_type(4))) float f32x4;
typedef __attribute__((ext_vector_type(4))) u32 u32x4v;

// ---- workspace layout (bytes), ws = 256 MiB ----
static const size_t OFF_NSBF = 0;            // N*64 bf16
static const size_t OFF_SV   = 2560000;      // N*64 * 4 fp16 (8B/ch)
static const size_t OFF_MG   = 23040000;     // N*512 f32
static const size_t OFF_TW   = 64000000;     // E*256 fp16, channel-major [c*4+q]
static const size_t OFF_W1F  = 227840000;    // 20480
static const size_t OFF_W2F  = 227860480;    // 8192
static const size_t OFF_W3F  = 227868672;    // 32768
static const size_t OFF_WNF  = 227901440;    // 49152
static const size_t OFF_CNT  = 227950592;    // 80000
static const size_t OFF_OFFS = 228030592;    // 80016
static const size_t OFF_CUR  = 228110608;    // 80000 (cursor only)
static const size_t OFF_SS   = 229470608;    // 1,280,000
static const size_t OFF_RS   = 230750608;    // 1,280,000
static const size_t OFF_EA   = 232030608;    // E*16B easort
static const size_t OFF_EF   = 237150608;    // E*16B efsort (8 bf16)
static const size_t OFF_LEN  = 242270608;    // E*2B lsort
static const size_t OFF_WSF  = 243550608;    // 64KB Ws/Wv hi-lo frags -> ends 243,616,144

static __device__ __forceinline__ u16 f2bf(float x) {
    union { float f; u32 u; } c; c.f = x;
    u32 u = c.u + 0x7fffu + ((c.u >> 16) & 1u);
    return (u16)(u >> 16);
}
static __device__ __forceinline__ float bf2f(u16 b) {
    union { u32 u; float f; } c; c.u = (u32)b << 16; return c.f;
}
static __device__ __forceinline__ u16 f2h(float x) {
    union { _Float16 h; u16 u; } c; c.h = (_Float16)x; return c.u;
}
static __device__ __forceinline__ float h2f(u32 b) {
    union { u16 u; _Float16 h; } c; c.u = (u16)b; return (float)c.h;
}
static __device__ __forceinline__ u32 pkh(float a, float b) {
    union { fp16x2 h; u32 u; } c;
    c.h = __builtin_amdgcn_cvt_pkrtz(a, b);
    return c.u;
}
static __device__ __forceinline__ f32x4 mfma16(short8 a, short8 b, f32x4 c) {
    return __builtin_amdgcn_mfma_f32_16x16x32_bf16(a, b, c, 0, 0, 0);
}
static __device__ __forceinline__ f32x4 mfma16h(half8 a, half8 b, f32x4 c) {
    return __builtin_amdgcn_mfma_f32_16x16x32_f16(a, b, c, 0, 0, 0);
}
static __device__ __forceinline__ float silu(float x) {
    return x / (1.0f + __expf(-x));
}
template <typename T>
static __device__ __forceinline__ T ntload(const T* p) { return __builtin_nontemporal_load(p); }
template <typename T>
static __device__ __forceinline__ void ntstore(T* p, T v) { __builtin_nontemporal_store(v, p); }

// ---- merged weight prep: W1/W2/W3 frags + Wsc/Wup frags + Ws/Wv hi-lo frags ----
__global__ void prep_all_kernel(const float* __restrict__ W1, const float* __restrict__ W2,
                                const float* __restrict__ W3,
                                const float* __restrict__ Wsc, const float* __restrict__ Wup0,
                                const float* __restrict__ Wup1,
                                const float* __restrict__ Ws, const float* __restrict__ Wv,
                                u16* __restrict__ W1f, u16* __restrict__ W2f,
                                u16* __restrict__ W3f, u16* __restrict__ WNF,
                                u16* __restrict__ WSF) {
    int t = blockIdx.x * 256 + threadIdx.x;
    if (t < 3840) {
        int l = t & 63, grp = t >> 6;
        int hi = l >> 4, lo = l & 15;
        if (grp < 20) {
            int kk = grp >> 2, jt = grp & 3;
#pragma unroll
            for (int e2 = 0; e2 < 8; e2++) {
                int k = kk * 32 + hi * 8 + e2, j = jt * 16 + lo;
                W1f[(size_t)(grp * 64 + l) * 8 + e2] = (k < 137) ? f2bf(W1[k * 64 + j]) : (u16)0;
            }
        } else if (grp < 28) {
            int g = grp - 20; int kk = g >> 2, jt = g & 3;
#pragma unroll
            for (int e2 = 0; e2 < 8; e2++) {
                int k = kk * 32 + hi * 8 + e2, j = jt * 16 + lo;
                int kp = ((k & 3) << 4) + (k >> 2);
                W2f[(size_t)(g * 64 + l) * 8 + e2] = f2h(W2[kp * 64 + j]);
            }
        } else {
            int g = grp - 28; int kk = g >> 4, jt = g & 15;
#pragma unroll
            for (int e2 = 0; e2 < 8; e2++) {
                int k = kk * 32 + hi * 8 + e2, j = jt * 16 + lo;
                int kp = ((k & 3) << 4) + (k >> 2);
                W3f[(size_t)(g * 64 + l) * 8 + e2] = f2h(W3[kp * 256 + j]);
            }
        }
    } else if (t < 5376) {
        int tt = t - 3840;
        int mat = tt >> 9;
        int rem = tt & 511;
        int g = rem >> 6, l = rem & 63;
        int kk = g >> 2, jt = g & 3, hi = l >> 4, lo = l & 15;
        const float* W = (mat == 0) ? Wsc : (mat == 1) ? Wup0 : Wup1;
        u16* dh = WNF + (size_t)mat * 8192 + (size_t)(g * 64 + l) * 8;
        u16* dl = dh + 4096;
#pragma unroll
        for (int e2 = 0; e2 < 8; e2++) {
            int k = kk * 32 + hi * 8 + e2, d = jt * 16 + lo;
            float w = W[k * 64 + d];
            u16 h = f2bf(w);
            dh[e2] = h;
            dl[e2] = f2bf(w - bf2f(h));
        }
    } else if (t < 7424) {
        int tt = t - 5376;
        int l = tt & 63, grp = tt >> 6;
        int wsel = grp >> 4;
        int g = grp & 15;
        int kk = g >> 2, jt = g & 3;
        int hi = l >> 4, lo = l & 15;
        const float* W = wsel ? Wv : Ws;
        u16* dh = WSF + (size_t)wsel * 16384;
        u16* dl = dh + 8192;
        size_t base = (size_t)(g * 64 + l) * 8;
#pragma unroll
        for (int e2 = 0; e2 < 8; e2++) {
            int k = kk * 32 + hi * 8 + e2, d = jt * 16 + lo;
            float w = W[k * 64 + d];
            u16 h = f2bf(w);
            float r = w - bf2f(h);
            dh[base + e2] = h;
            dl[base + e2] = f2bf(r);
        }
    }
}

// ---- node precompute: MFMA, hi/lo split A; sv output packed fp16 ----
__global__ __launch_bounds__(256) void node_prep_kernel(
    const float* __restrict__ node_feats, const u16* __restrict__ WNF,
    u16* __restrict__ ns_bf, u16* __restrict__ svh) {
    const int tid = threadIdx.x;
    const int lane = tid & 63;
    const int w = tid >> 6;
    const int lo16 = lane & 15;
    const int hi = lane >> 4;
    const int nb = blockIdx.x * 64 + w * 16;

    int an = nb + lo16; if (an > N_NODES - 1) an = N_NODES - 1;
    const float* arow = node_feats + (size_t)an * 256;

    const short8* B = (const short8*)WNF;

    f32x4 acc_ns[4], acc_su[4], acc_v[3][4];
#pragma unroll
    for (int jt = 0; jt < 4; jt++) {
        acc_ns[jt] = (f32x4)(0.0f);
        acc_su[jt] = (f32x4)(0.0f);
#pragma unroll
        for (int i = 0; i < 3; i++) acc_v[i][jt] = (f32x4)(0.0f);
    }

#pragma unroll
    for (int kk = 0; kk < 2; kk++) {
        short8 sh, sl;
        {
            const float* sp = arow + kk * 32 + hi * 8;
            f32x4 x0 = *(const f32x4*)sp;
            f32x4 x1 = *(const f32x4*)(sp + 4);
#pragma unroll
            for (int j = 0; j < 4; j++) {
                u16 h0 = f2bf(x0[j]);
                sh[j] = (short)h0;
                sl[j] = (short)f2bf(x0[j] - bf2f(h0));
                u16 h1 = f2bf(x1[j]);
                sh[4 + j] = (short)h1;
                sl[4 + j] = (short)f2bf(x1[j] - bf2f(h1));
            }
        }
        short8 vh[3], vl[3];
#pragma unroll
        for (int i = 0; i < 3; i++) {
            const float* vp = arow + 64 + i + 3 * (kk * 32 + hi * 8);
#pragma unroll
            for (int e = 0; e < 8; e++) {
                float x = vp[e * 3];
                u16 hb = f2bf(x);
                vh[i][e] = (short)hb;
                vl[i][e] = (short)f2bf(x - bf2f(hb));
            }
        }
#pragma unroll
        for (int jt = 0; jt < 4; jt++) {
            int fi = (kk * 4 + jt) * 64 + lane;
            short8 bh = B[fi], bl = B[512 + fi];
            acc_ns[jt] = mfma16(sh, bh, acc_ns[jt]);
            acc_ns[jt] = mfma16(sl, bh, acc_ns[jt]);
            acc_ns[jt] = mfma16(sh, bl, acc_ns[jt]);
            bh = B[1024 + fi]; bl = B[1536 + fi];
            acc_su[jt] = mfma16(sh, bh, acc_su[jt]);
            acc_su[jt] = mfma16(sl, bh, acc_su[jt]);
            acc_su[jt] = mfma16(sh, bl, acc_su[jt]);
            bh = B[2048 + fi]; bl = B[2560 + fi];
#pragma unroll
            for (int i = 0; i < 3; i++) {
                acc_v[i][jt] = mfma16(vh[i], bh, acc_v[i][jt]);
                acc_v[i][jt] = mfma16(vl[i], bh, acc_v[i][jt]);
                acc_v[i][jt] = mfma16(vh[i], bl, acc_v[i][jt]);
            }
        }
    }

#pragma unroll
    for (int r = 0; r < 4; r++) {
        int n = nb + hi * 4 + r;
        if (n < N_NODES) {
#pragma unroll
            for (int jt = 0; jt < 4; jt++) {
                int d = jt * 16 + lo16;
                ns_bf[(size_t)n * 64 + d] = f2bf(acc_ns[jt][r]);
                uint2 o;
                o.x = pkh(acc_su[jt][r], acc_v[0][jt][r]);
                o.y = pkh(acc_v[1][jt][r], acc_v[2][jt][r]);
                *(uint2*)&svh[((size_t)n * 64 + d) * 4] = o;
            }
        }
    }
}

// ---- counting sort by rcv ----
__global__ void hist_kernel(const int* __restrict__ ei, int* __restrict__ cnt) {
    int e = blockIdx.x * 256 + threadIdx.x;
    if (e < N_EDGES) atomicAdd(&cnt[ei[N_EDGES + e]], 1);
}

__global__ void scan_kernel(const int* __restrict__ cnt, int* __restrict__ offs,
                            int* __restrict__ cursor) {
    __shared__ int buf[1024];
    int t = threadIdx.x;
    int base = t * 20;
    int loc[20];
    int tot = 0;
    int v20[20];
    if (base < N_NODES) {
#pragma unroll
        for (int q = 0; q < 5; q++) {
            int4 vv = *(const int4*)&cnt[base + q * 4];
            v20[q * 4 + 0] = vv.x; v20[q * 4 + 1] = vv.y;
            v20[q * 4 + 2] = vv.z; v20[q * 4 + 3] = vv.w;
        }
    } else {
#pragma unroll
        for (int i = 0; i < 20; i++) v20[i] = 0;
    }
#pragma unroll
    for (int i = 0; i < 20; i++) { loc[i] = tot; tot += v20[i]; }
    buf[t] = tot;
    __syncthreads();
    for (int d = 1; d < 1024; d <<= 1) {
        int add = (t >= d) ? buf[t - d] : 0;
        __syncthreads();
        buf[t] += add;
        __syncthreads();
    }
    int ebase = buf[t] - tot;
#pragma unroll
    for (int i = 0; i < 20; i++) {
        int idx = base + i;
        if (idx < N_NODES) { int o = ebase + loc[i]; offs[idx] = o; cursor[idx] = o; }
    }
    if (t == 1023) offs[N_NODES] = buf[1023];
}

// ---- scatter: sort + pre-gather edge payloads into sorted order ----
__global__ void scatter_kernel(const int* __restrict__ ei, const float* __restrict__ edge_attrs,
                               const float* __restrict__ edge_feats, const float* __restrict__ lengths,
                               int* __restrict__ cursor,
                               int* __restrict__ ssort, int* __restrict__ rsort,
                               float* __restrict__ easort, u16* __restrict__ efsort,
                               u16* __restrict__ lsort) {
    int e = blockIdx.x * 256 + threadIdx.x;
    if (e < N_EDGES) {
        int sn = ei[e];
        int rc = ei[N_EDGES + e];
        float4 ea = *(const float4*)(edge_attrs + (size_t)e * 4);
        float4 f0 = *(const float4*)(edge_feats + (size_t)e * 8);
        float4 f1 = *(const float4*)(edge_feats + (size_t)e * 8 + 4);
        float len = lengths[e];
        uint4 pk;
        pk.x = (u32)f2bf(f0.x) | ((u32)f2bf(f0.y) << 16);
        pk.y = (u32)f2bf(f0.z) | ((u32)f2bf(f0.w) << 16);
        pk.z = (u32)f2bf(f1.x) | ((u32)f2bf(f1.y) << 16);
        pk.w = (u32)f2bf(f1.z) | ((u32)f2bf(f1.w) << 16);
        int pos = atomicAdd(&cursor[rc], 1);
        ssort[pos] = sn;
        rsort[pos] = rc;
        *(float4*)(easort + (size_t)pos * 4) = ea;
        *(uint4*)(efsort + (size_t)pos * 8) = pk;
        lsort[pos] = f2bf(len);
    }
}

// ---- K3: edge MLP. Two LDS buffers, all rows wave-private:
//      mlpbuf = staging (read-only after stage); hbuf = h1 then h2 (wave w's rows
//      [16w,16w+16) written/read only by wave w, in program order) -> race-free,
//      NO barriers; setprio(1) around MFMA clusters. 30.7KB LDS, 5 blocks/CU. ----
__global__ __launch_bounds__(256, 5) void mlp_kernel(
    const u16* __restrict__ ns_bf,
    const u16* __restrict__ W1f, const u16* __restrict__ W2f, const u16* __restrict__ W3f,
    const float* __restrict__ b1, const float* __restrict__ b2,
    const int* __restrict__ ssort, const int* __restrict__ rsort,
    const u16* __restrict__ efsort, const u16* __restrict__ lsort,
    u16* __restrict__ twg) {

    __shared__ u16 mlpbuf[64][168];   // staging only
    __shared__ u16 hbuf[64][72];      // h1, then h2 (row-private reuse)

    const int tid = threadIdx.x;
    const int l = tid & 63;
    const int lo16 = l & 15;
    const int hi = l >> 4;
    const int w = tid >> 6;
    const int erow = (w << 4) | lo16;
    const int koff = hi * 8;
    const int drow = (w << 4) + hi * 4;

    // XCD-aware swizzle: grid 5000 = 8 XCDs x 625 contiguous blocks
    const int nwg = N_EDGES / 64;
    const int cpx = nwg / 8;
    const int bid = (int)blockIdx.x;
    const int swz = (bid % 8) * cpx + bid / 8;
    const int p0 = swz * 64;

    const short8* w1frag = (const short8*)W1f;
    const half8* w2frag = (const half8*)W2f;
    const half8* w3frag = (const half8*)W3f;

    float bb1[4], bb2[4];
#pragma unroll
    for (int jt = 0; jt < 4; jt++) { bb1[jt] = b1[jt * 16 + lo16]; bb2[jt] = b2[jt * 16 + lo16]; }

    // zero pad region k=136..167 (wave-private rows)
    {
        int rr = tid >> 2, pp = tid & 3;
        uint4 z = {0, 0, 0, 0};
        *(uint4*)&mlpbuf[rr][136 + pp * 8] = z;
    }

    // stage gathered edge inputs (wave-private rows)
    {
        int es = tid >> 2, part = tid & 3;
        int sn = ssort[p0 + es];
        int rc = rsort[p0 + es];
        const uint4* ps = (const uint4*)(ns_bf + (size_t)sn * 64 + part * 16);
        uint4 s0 = ps[0], s1 = ps[1];
        *(uint4*)&mlpbuf[es][part * 16] = s0;
        *(uint4*)&mlpbuf[es][part * 16 + 8] = s1;
        const uint4* pr = (const uint4*)(ns_bf + (size_t)rc * 64 + part * 16);
        uint4 r0v = pr[0], r1v = pr[1];
        *(uint4*)&mlpbuf[es][64 + part * 16] = r0v;
        *(uint4*)&mlpbuf[es][64 + part * 16 + 8] = r1v;
        if (part == 0) {
            uint4 pk = *(const uint4*)(efsort + (size_t)(p0 + es) * 8);
            *(uint4*)&mlpbuf[es][128] = pk;
            mlpbuf[es][136] = lsort[p0 + es];
        }
    }
    // no barrier: rows are wave-private; per-wave in-order DS execution suffices

    // layer 1: (64x160) @ (160x64), bf16
    f32x4 a1c[4];
#pragma unroll
    for (int jt = 0; jt < 4; jt++) a1c[jt] = (f32x4)(0.0f);
    __builtin_amdgcn_s_setprio(1);
#pragma unroll
    for (int kk = 0; kk < 5; kk++) {
        short8 af = *(const short8*)&mlpbuf[erow][kk * 32 + koff];
        const short8* wb = w1frag + kk * 256 + l;
        a1c[0] = mfma16(af, wb[0],   a1c[0]);
        a1c[1] = mfma16(af, wb[64],  a1c[1]);
        a1c[2] = mfma16(af, wb[128], a1c[2]);
        a1c[3] = mfma16(af, wb[192], a1c[3]);
    }
    __builtin_amdgcn_s_setprio(0);
    // h1 -> hbuf rows drow..drow+3 (wave-private)
#pragma unroll
    for (int r = 0; r < 4; r++) {
        uint2 pk;
        pk.x = pkh(silu(a1c[0][r] + bb1[0]), silu(a1c[1][r] + bb1[1]));
        pk.y = pkh(silu(a1c[2][r] + bb1[2]), silu(a1c[3][r] + bb1[3]));
        *(uint2*)&hbuf[drow + r][lo16 * 4] = pk;
    }

    // layer 2: (64x64) @ (64x64), fp16 (permuted K); h1 in hbuf
    f32x4 a2c[4];
#pragma unroll
    for (int jt = 0; jt < 4; jt++) a2c[jt] = (f32x4)(0.0f);
    __builtin_amdgcn_s_setprio(1);
#pragma unroll
    for (int kk = 0; kk < 2; kk++) {
        half8 af = *(const half8*)&hbuf[erow][kk * 32 + koff];
        const half8* wb = w2frag + kk * 256 + l;
        a2c[0] = mfma16h(af, wb[0],   a2c[0]);
        a2c[1] = mfma16h(af, wb[64],  a2c[1]);
        a2c[2] = mfma16h(af, wb[128], a2c[2]);
        a2c[3] = mfma16h(af, wb[192], a2c[3]);
    }
    __builtin_amdgcn_s_setprio(0);
    // h2 overwrites h1 in hbuf (same wave's rows; its L2 reads of those rows are done)
#pragma unroll
    for (int r = 0; r < 4; r++) {
        uint2 pk;
        pk.x = pkh(silu(a2c[0][r] + bb2[0]), silu(a2c[1][r] + bb2[1]));
        pk.y = pkh(silu(a2c[2][r] + bb2[2]), silu(a2c[3][r] + bb2[3]));
        *(uint2*)&hbuf[drow + r][lo16 * 4] = pk;
    }

    // layer 3: (64x64) @ (64x256), fp16 (permuted K); h2 in hbuf
    f32x4 tw[16];
#pragma unroll
    for (int jt = 0; jt < 16; jt++) tw[jt] = (f32x4)(0.0f);
    __builtin_amdgcn_s_setprio(1);
#pragma unroll
    for (int kk = 0; kk < 2; kk++) {
        half8 af = *(const half8*)&hbuf[erow][kk * 32 + koff];
        const half8* wb = w3frag + kk * 1024 + l;
#pragma unroll
        for (int jt = 0; jt < 16; jt++) tw[jt] = mfma16h(af, wb[jt * 64], tw[jt]);
    }
    __builtin_amdgcn_s_setprio(0);

    // store tw channel-major: tw[jt] -> q = jt>>2, c = (jt&3)*16+lo16; twg[e*256 + c*4 + q]
    int relrow = p0 + drow;
#pragma unroll
    for (int r = 0; r < 4; r++) {
        u16* dst = twg + (size_t)(relrow + r) * 256 + lo16 * 4;
#pragma unroll
        for (int jt4 = 0; jt4 < 4; jt4++) {
            uint2 pk;
            pk.x = pkh(tw[jt4][r],     tw[4 + jt4][r]);
            pk.y = pkh(tw[8 + jt4][r], tw[12 + jt4][r]);
            *(uint2*)(dst + jt4 * 64) = pk;
        }
    }
}

// ---- K4: one wave per node; tensor products + register segment-sum;
//      channel-major tw; XCD-swizzled blockIdx ----
__global__ __launch_bounds__(256, 4) void seg_kernel(
    const u16* __restrict__ svh, const float* __restrict__ easort,
    const int* __restrict__ ssort,
    const int* __restrict__ offs, const u16* __restrict__ twg,
    float* __restrict__ m_g) {
    const int lane = threadIdx.x & 63;
    const int wv = threadIdx.x >> 6;
    const int nwg = N_NODES / 4;
    const int cpx = nwg / 8;
    const int bid = (int)blockIdx.x;
    const int swz = (bid % 8) * cpx + bid / 8;
    const int n = swz * 4 + wv;
    const int c = lane;
    const int e0 = offs[n], e1 = offs[n + 1];
    float a_m0 = 0.f, a_m0b = 0.f;
    float a20 = 0.f, a21 = 0.f, a22 = 0.f, a30 = 0.f, a31 = 0.f, a32 = 0.f;
#pragma unroll 4
    for (int pos = e0; pos < e1; ++pos) {
        int sn = ssort[pos];
        uint2 tq = *(const uint2*)(twg + (size_t)pos * 256 + c * 4);
        f32x4 y4 = *(const f32x4*)(easort + (size_t)pos * 4);
        uint2 sp = *(const uint2*)&svh[((size_t)sn * 64 + c) * 4];
        float w0 = h2f(tq.x & 0xffffu);
        float w1 = h2f(tq.x >> 16);
        float w2 = h2f(tq.y & 0xffffu);
        float w3 = h2f(tq.y >> 16);
        float xs  = h2f(sp.x & 0xffffu);
        float xv0 = h2f(sp.x >> 16);
        float xv1 = h2f(sp.y & 0xffffu);
        float xv2 = h2f(sp.y >> 16);
        float y0 = y4.x, ya = y4.y, yb = y4.z, yc = y4.w;
        a_m0 = fmaf(xs * y0, w0, a_m0);
        float dv = xv0 * ya + xv1 * yb + xv2 * yc;
        a_m0b = fmaf(dv, w1, a_m0b);
        float sw2 = xs * w2;
        a20 = fmaf(sw2, ya, a20); a21 = fmaf(sw2, yb, a21); a22 = fmaf(sw2, yc, a22);
        float yw3 = y0 * w3;
        a30 = fmaf(xv0, yw3, a30); a31 = fmaf(xv1, yw3, a31); a32 = fmaf(xv2, yw3, a32);
    }
    float* mr = m_g + (size_t)n * 512;
    ntstore(mr + c,        a_m0);
    ntstore(mr + 64 + c,   a_m0b * INV_SQRT3);
    ntstore(mr + 128 + c,  a20);
    ntstore(mr + 192 + c,  a30);
    ntstore(mr + 256 + c,  a21);
    ntstore(mr + 320 + c,  a31);
    ntstore(mr + 384 + c,  a22);
    ntstore(mr + 448 + c,  a32);
}

// ---- K5: MFMA epilogue. 64 nodes/block, 4 waves, no LDS, no barriers. ----
__global__ __launch_bounds__(256, 2) void out_kernel(
    const float* __restrict__ m_g, const u16* __restrict__ WSF,
    float* __restrict__ out) {
    const int tid = threadIdx.x;
    const int lane = tid & 63;
    const int w = tid >> 6;
    const int lo16 = lane & 15;
    const int hi = lane >> 4;
    const int nb = blockIdx.x * 64 + w * 16;

    int arow_n = nb + lo16;
    if (arow_n > N_NODES - 1) arow_n = N_NODES - 1;
    const float* arow = m_g + (size_t)arow_n * 512 + hi * 8;

    const short8* bsh = (const short8*)WSF;
    const short8* bsl = (const short8*)(WSF + 8192);
    const short8* bvh = (const short8*)(WSF + 16384);
    const short8* bvl = (const short8*)(WSF + 24576);

    f32x4 acc[4][4];
#pragma unroll
    for (int q = 0; q < 4; q++)
#pragma unroll
        for (int jt = 0; jt < 4; jt++) acc[q][jt] = (f32x4)(0.0f);

#pragma unroll
    for (int kk = 0; kk < 4; kk++) {
        short8 ahi[4], alo[4];
#pragma unroll
        for (int q = 0; q < 4; q++) {
            const float* p = arow + q * 128 + kk * 32;
            f32x4 x0 = ntload((const f32x4*)p);
            f32x4 x1 = ntload((const f32x4*)(p + 4));
#pragma unroll
            for (int j = 0; j < 4; j++) {
                u16 h0 = f2bf(x0[j]);
                ahi[q][j] = (short)h0;
                alo[q][j] = (short)f2bf(x0[j] - bf2f(h0));
                u16 h1 = f2bf(x1[j]);
                ahi[q][4 + j] = (short)h1;
                alo[q][4 + j] = (short)f2bf(x1[j] - bf2f(h1));
            }
        }
#pragma unroll
        for (int jt = 0; jt < 4; jt++) {
            int bidx = (kk * 4 + jt) * 64 + lane;
            short8 wh_s = bsh[bidx];
            short8 wl_s = bsl[bidx];
            short8 wh_v = bvh[bidx];
            short8 wl_v = bvl[bidx];
            acc[0][jt] = mfma16(ahi[0], wh_s, acc[0][jt]);
            acc[0][jt] = mfma16(alo[0], wh_s, acc[0][jt]);
            acc[0][jt] = mfma16(ahi[0], wl_s, acc[0][jt]);
#pragma unroll
            for (int q = 1; q < 4; q++) {
                acc[q][jt] = mfma16(ahi[q], wh_v, acc[q][jt]);
                acc[q][jt] = mfma16(alo[q], wh_v, acc[q][jt]);
                acc[q][jt] = mfma16(ahi[q], wl_v, acc[q][jt]);
            }
        }
    }

#pragma unroll
    for (int r = 0; r < 4; r++) {
        int n = nb + hi * 4 + r;
        if (n < N_NODES) {
#pragma unroll
            for (int jt = 0; jt < 4; jt++) {
                int d = jt * 16 + lo16;
                f32x4 o;
                o.x = acc[0][jt][r] * 0.0625f;
                o.y = acc[1][jt][r] * 0.0625f;
                o.z = acc[2][jt][r] * 0.0625f;
                o.w = acc[3][jt][r] * 0.0625f;
                ntstore((f32x4*)(out + (size_t)n * 256 + d * 4), o);
            }
        }
    }
}

extern "C" void kernel_launch(void* const* d_in, const int* in_sizes, int n_in,
                              void* d_out, int out_size, void* d_ws, size_t ws_size,
                              hipStream_t stream) {
    (void)in_sizes; (void)n_in; (void)out_size; (void)ws_size;
    const float* node_feats = (const float*)d_in[0];
    const float* edge_attrs = (const float*)d_in[1];
    const float* edge_feats = (const float*)d_in[2];
    const float* lengths    = (const float*)d_in[3];
    const int*   edge_index = (const int*)d_in[4];
    const float* Wsc  = (const float*)d_in[5];
    const float* Wup0 = (const float*)d_in[6];
    const float* Wup1 = (const float*)d_in[7];
    const float* W1   = (const float*)d_in[8];
    const float* b1   = (const float*)d_in[9];
    const float* W2   = (const float*)d_in[10];
    const float* b2   = (const float*)d_in[11];
    const float* W3   = (const float*)d_in[12];
    const float* Ws   = (const float*)d_in[13];
    const float* Wv   = (const float*)d_in[14];

    char* ws = (char*)d_ws;
    u16*   ns_bf  = (u16*)(ws + OFF_NSBF);
    u16*   svh    = (u16*)(ws + OFF_SV);
    float* m_g    = (float*)(ws + OFF_MG);
    u16*   twg    = (u16*)(ws + OFF_TW);
    u16*   W1f    = (u16*)(ws + OFF_W1F);
    u16*   W2f    = (u16*)(ws + OFF_W2F);
    u16*   W3f    = (u16*)(ws + OFF_W3F);
    u16*   WNF    = (u16*)(ws + OFF_WNF);
    int*   cnt    = (int*)(ws + OFF_CNT);
    int*   offs   = (int*)(ws + OFF_OFFS);
    int*   cursor = (int*)(ws + OFF_CUR);
    u16*   WSF    = (u16*)(ws + OFF_WSF);
    int*   ssort  = (int*)(ws + OFF_SS);
    int*   rsort  = (int*)(ws + OFF_RS);
    float* easort = (float*)(ws + OFF_EA);
    u16*   efsort = (u16*)(ws + OFF_EF);
    u16*   lsort  = (u16*)(ws + OFF_LEN);
    float* out    = (float*)d_out;

    (void)hipMemsetAsync(cnt, 0, N_NODES * sizeof(int), stream);
    prep_all_kernel<<<29, 256, 0, stream>>>(W1, W2, W3, Wsc, Wup0, Wup1, Ws, Wv,
                                            W1f, W2f, W3f, WNF, WSF);
    node_prep_kernel<<<(N_NODES + 63) / 64, 256, 0, stream>>>(node_feats, WNF, ns_bf, svh);
    hist_kernel<<<N_EDGES / 256, 256, 0, stream>>>(edge_index, cnt);
    scan_kernel<<<1, 1024, 0, stream>>>(cnt, offs, cursor);
    scatter_kernel<<<N_EDGES / 256, 256, 0, stream>>>(edge_index, edge_attrs, edge_feats,
                                                      lengths, cursor,
                                                      ssort, rsort, easort, efsort, lsort);

    mlp_kernel<<<N_EDGES / 64, 256, 0, stream>>>(ns_bf, W1f, W2f, W3f, b1, b2,
                                                 ssort, rsort, efsort, lsort, twg);
    seg_kernel<<<N_NODES / 4, 256, 0, stream>>>(svh, easort, ssort,
                                                offs, twg, m_g);
    out_kernel<<<(N_NODES + 63) / 64, 256, 0, stream>>>(m_g, WSF, out);
}

// Round 20
// 227.939 us; speedup vs baseline: 1.1722x; 1.0136x over previous
//
#include <hip/hip_runtime.h>

#define N_NODES 20000
#define N_EDGES 320000
#define INV_SQRT3 0.5773502691896258f

typedef unsigned short u16;
typedef unsigned int u32;
typedef __attribute__((ext_vector_type(8))) short short8;
typedef __attribute__((ext_vector_type(8))) _Float16 half8;
typedef __attribute__((ext_vector_type(2))) __fp16 fp16x2;
typedef __attribute__((ext_vector_type(4))) float f32x4;
typedef __attribute__((ext_vector_type(4))) u32 u32x4v;

// ---- workspace layout (bytes), ws = 256 MiB ----
static const size_t OFF_NSBF = 0;            // N*64 bf16
static const size_t OFF_SV   = 2560000;      // N*64 * 4 fp16 (8B/ch)
static const size_t OFF_MG   = 23040000;     // N*512 f32
static const size_t OFF_TW   = 64000000;     // E*256 fp16, channel-major [c*4+q]
static const size_t OFF_W1F  = 227840000;    // 20480
static const size_t OFF_W2F  = 227860480;    // 8192
static const size_t OFF_W3F  = 227868672;    // 32768
static const size_t OFF_WNF  = 227901440;    // 49152
static const size_t OFF_CNT  = 227950592;    // 80000
static const size_t OFF_OFFS = 228030592;    // 80016
static const size_t OFF_CUR  = 228110608;    // 80000 (cursor only)
static const size_t OFF_SS   = 229470608;    // 1,280,000
static const size_t OFF_RS   = 230750608;    // 1,280,000
static const size_t OFF_EA   = 232030608;    // E*16B easort
static const size_t OFF_EF   = 237150608;    // E*16B efsort (8 bf16)
static const size_t OFF_LEN  = 242270608;    // E*2B lsort
static const size_t OFF_WSF  = 243550608;    // 64KB Ws/Wv hi-lo frags -> ends 243,616,144

static __device__ __forceinline__ u16 f2bf(float x) {
    union { float f; u32 u; } c; c.f = x;
    u32 u = c.u + 0x7fffu + ((c.u >> 16) & 1u);
    return (u16)(u >> 16);
}
static __device__ __forceinline__ float bf2f(u16 b) {
    union { u32 u; float f; } c; c.u = (u32)b << 16; return c.f;
}
static __device__ __forceinline__ u16 f2h(float x) {
    union { _Float16 h; u16 u; } c; c.h = (_Float16)x; return c.u;
}
static __device__ __forceinline__ float h2f(u32 b) {
    union { u16 u; _Float16 h; } c; c.u = (u16)b; return (float)c.h;
}
static __device__ __forceinline__ u32 pkh(float a, float b) {
    union { fp16x2 h; u32 u; } c;
    c.h = __builtin_amdgcn_cvt_pkrtz(a, b);
    return c.u;
}
static __device__ __forceinline__ f32x4 mfma16(short8 a, short8 b, f32x4 c) {
    return __builtin_amdgcn_mfma_f32_16x16x32_bf16(a, b, c, 0, 0, 0);
}
static __device__ __forceinline__ f32x4 mfma16h(half8 a, half8 b, f32x4 c) {
    return __builtin_amdgcn_mfma_f32_16x16x32_f16(a, b, c, 0, 0, 0);
}
static __device__ __forceinline__ float silu(float x) {
    return x / (1.0f + __expf(-x));
}
template <typename T>
static __device__ __forceinline__ T ntload(const T* p) { return __builtin_nontemporal_load(p); }
template <typename T>
static __device__ __forceinline__ void ntstore(T* p, T v) { __builtin_nontemporal_store(v, p); }

// ---- merged weight prep: W1/W2/W3 frags + Wsc/Wup frags + Ws/Wv hi-lo frags ----
__global__ void prep_all_kernel(const float* __restrict__ W1, const float* __restrict__ W2,
                                const float* __restrict__ W3,
                                const float* __restrict__ Wsc, const float* __restrict__ Wup0,
                                const float* __restrict__ Wup1,
                                const float* __restrict__ Ws, const float* __restrict__ Wv,
                                u16* __restrict__ W1f, u16* __restrict__ W2f,
                                u16* __restrict__ W3f, u16* __restrict__ WNF,
                                u16* __restrict__ WSF) {
    int t = blockIdx.x * 256 + threadIdx.x;
    if (t < 3840) {
        int l = t & 63, grp = t >> 6;
        int hi = l >> 4, lo = l & 15;
        if (grp < 20) {
            int kk = grp >> 2, jt = grp & 3;
#pragma unroll
            for (int e2 = 0; e2 < 8; e2++) {
                int k = kk * 32 + hi * 8 + e2, j = jt * 16 + lo;
                W1f[(size_t)(grp * 64 + l) * 8 + e2] = (k < 137) ? f2bf(W1[k * 64 + j]) : (u16)0;
            }
        } else if (grp < 28) {
            int g = grp - 20; int kk = g >> 2, jt = g & 3;
#pragma unroll
            for (int e2 = 0; e2 < 8; e2++) {
                int k = kk * 32 + hi * 8 + e2, j = jt * 16 + lo;
                int kp = ((k & 3) << 4) + (k >> 2);
                W2f[(size_t)(g * 64 + l) * 8 + e2] = f2h(W2[kp * 64 + j]);
            }
        } else {
            int g = grp - 28; int kk = g >> 4, jt = g & 15;
#pragma unroll
            for (int e2 = 0; e2 < 8; e2++) {
                int k = kk * 32 + hi * 8 + e2, j = jt * 16 + lo;
                int kp = ((k & 3) << 4) + (k >> 2);
                W3f[(size_t)(g * 64 + l) * 8 + e2] = f2h(W3[kp * 256 + j]);
            }
        }
    } else if (t < 5376) {
        int tt = t - 3840;
        int mat = tt >> 9;
        int rem = tt & 511;
        int g = rem >> 6, l = rem & 63;
        int kk = g >> 2, jt = g & 3, hi = l >> 4, lo = l & 15;
        const float* W = (mat == 0) ? Wsc : (mat == 1) ? Wup0 : Wup1;
        u16* dh = WNF + (size_t)mat * 8192 + (size_t)(g * 64 + l) * 8;
        u16* dl = dh + 4096;
#pragma unroll
        for (int e2 = 0; e2 < 8; e2++) {
            int k = kk * 32 + hi * 8 + e2, d = jt * 16 + lo;
            float w = W[k * 64 + d];
            u16 h = f2bf(w);
            dh[e2] = h;
            dl[e2] = f2bf(w - bf2f(h));
        }
    } else if (t < 7424) {
        int tt = t - 5376;
        int l = tt & 63, grp = tt >> 6;
        int wsel = grp >> 4;
        int g = grp & 15;
        int kk = g >> 2, jt = g & 3;
        int hi = l >> 4, lo = l & 15;
        const float* W = wsel ? Wv : Ws;
        u16* dh = WSF + (size_t)wsel * 16384;
        u16* dl = dh + 8192;
        size_t base = (size_t)(g * 64 + l) * 8;
#pragma unroll
        for (int e2 = 0; e2 < 8; e2++) {
            int k = kk * 32 + hi * 8 + e2, d = jt * 16 + lo;
            float w = W[k * 64 + d];
            u16 h = f2bf(w);
            float r = w - bf2f(h);
            dh[base + e2] = h;
            dl[base + e2] = f2bf(r);
        }
    }
}

// ---- node precompute: MFMA, hi/lo split A; sv output packed fp16 ----
__global__ __launch_bounds__(256) void node_prep_kernel(
    const float* __restrict__ node_feats, const u16* __restrict__ WNF,
    u16* __restrict__ ns_bf, u16* __restrict__ svh) {
    const int tid = threadIdx.x;
    const int lane = tid & 63;
    const int w = tid >> 6;
    const int lo16 = lane & 15;
    const int hi = lane >> 4;
    const int nb = blockIdx.x * 64 + w * 16;

    int an = nb + lo16; if (an > N_NODES - 1) an = N_NODES - 1;
    const float* arow = node_feats + (size_t)an * 256;

    const short8* B = (const short8*)WNF;

    f32x4 acc_ns[4], acc_su[4], acc_v[3][4];
#pragma unroll
    for (int jt = 0; jt < 4; jt++) {
        acc_ns[jt] = (f32x4)(0.0f);
        acc_su[jt] = (f32x4)(0.0f);
#pragma unroll
        for (int i = 0; i < 3; i++) acc_v[i][jt] = (f32x4)(0.0f);
    }

#pragma unroll
    for (int kk = 0; kk < 2; kk++) {
        short8 sh, sl;
        {
            const float* sp = arow + kk * 32 + hi * 8;
            f32x4 x0 = *(const f32x4*)sp;
            f32x4 x1 = *(const f32x4*)(sp + 4);
#pragma unroll
            for (int j = 0; j < 4; j++) {
                u16 h0 = f2bf(x0[j]);
                sh[j] = (short)h0;
                sl[j] = (short)f2bf(x0[j] - bf2f(h0));
                u16 h1 = f2bf(x1[j]);
                sh[4 + j] = (short)h1;
                sl[4 + j] = (short)f2bf(x1[j] - bf2f(h1));
            }
        }
        short8 vh[3], vl[3];
#pragma unroll
        for (int i = 0; i < 3; i++) {
            const float* vp = arow + 64 + i + 3 * (kk * 32 + hi * 8);
#pragma unroll
            for (int e = 0; e < 8; e++) {
                float x = vp[e * 3];
                u16 hb = f2bf(x);
                vh[i][e] = (short)hb;
                vl[i][e] = (short)f2bf(x - bf2f(hb));
            }
        }
#pragma unroll
        for (int jt = 0; jt < 4; jt++) {
            int fi = (kk * 4 + jt) * 64 + lane;
            short8 bh = B[fi], bl = B[512 + fi];
            acc_ns[jt] = mfma16(sh, bh, acc_ns[jt]);
            acc_ns[jt] = mfma16(sl, bh, acc_ns[jt]);
            acc_ns[jt] = mfma16(sh, bl, acc_ns[jt]);
            bh = B[1024 + fi]; bl = B[1536 + fi];
            acc_su[jt] = mfma16(sh, bh, acc_su[jt]);
            acc_su[jt] = mfma16(sl, bh, acc_su[jt]);
            acc_su[jt] = mfma16(sh, bl, acc_su[jt]);
            bh = B[2048 + fi]; bl = B[2560 + fi];
#pragma unroll
            for (int i = 0; i < 3; i++) {
                acc_v[i][jt] = mfma16(vh[i], bh, acc_v[i][jt]);
                acc_v[i][jt] = mfma16(vl[i], bh, acc_v[i][jt]);
                acc_v[i][jt] = mfma16(vh[i], bl, acc_v[i][jt]);
            }
        }
    }

#pragma unroll
    for (int r = 0; r < 4; r++) {
        int n = nb + hi * 4 + r;
        if (n < N_NODES) {
#pragma unroll
            for (int jt = 0; jt < 4; jt++) {
                int d = jt * 16 + lo16;
                ns_bf[(size_t)n * 64 + d] = f2bf(acc_ns[jt][r]);
                uint2 o;
                o.x = pkh(acc_su[jt][r], acc_v[0][jt][r]);
                o.y = pkh(acc_v[1][jt][r], acc_v[2][jt][r]);
                *(uint2*)&svh[((size_t)n * 64 + d) * 4] = o;
            }
        }
    }
}

// ---- counting sort by rcv ----
__global__ void hist_kernel(const int* __restrict__ ei, int* __restrict__ cnt) {
    int e = blockIdx.x * 256 + threadIdx.x;
    if (e < N_EDGES) atomicAdd(&cnt[ei[N_EDGES + e]], 1);
}

__global__ void scan_kernel(const int* __restrict__ cnt, int* __restrict__ offs,
                            int* __restrict__ cursor) {
    __shared__ int buf[1024];
    int t = threadIdx.x;
    int base = t * 20;
    int loc[20];
    int tot = 0;
    int v20[20];
    if (base < N_NODES) {
#pragma unroll
        for (int q = 0; q < 5; q++) {
            int4 vv = *(const int4*)&cnt[base + q * 4];
            v20[q * 4 + 0] = vv.x; v20[q * 4 + 1] = vv.y;
            v20[q * 4 + 2] = vv.z; v20[q * 4 + 3] = vv.w;
        }
    } else {
#pragma unroll
        for (int i = 0; i < 20; i++) v20[i] = 0;
    }
#pragma unroll
    for (int i = 0; i < 20; i++) { loc[i] = tot; tot += v20[i]; }
    buf[t] = tot;
    __syncthreads();
    for (int d = 1; d < 1024; d <<= 1) {
        int add = (t >= d) ? buf[t - d] : 0;
        __syncthreads();
        buf[t] += add;
        __syncthreads();
    }
    int ebase = buf[t] - tot;
#pragma unroll
    for (int i = 0; i < 20; i++) {
        int idx = base + i;
        if (idx < N_NODES) { int o = ebase + loc[i]; offs[idx] = o; cursor[idx] = o; }
    }
    if (t == 1023) offs[N_NODES] = buf[1023];
}

// ---- scatter: sort + pre-gather edge payloads into sorted order ----
__global__ void scatter_kernel(const int* __restrict__ ei, const float* __restrict__ edge_attrs,
                               const float* __restrict__ edge_feats, const float* __restrict__ lengths,
                               int* __restrict__ cursor,
                               int* __restrict__ ssort, int* __restrict__ rsort,
                               float* __restrict__ easort, u16* __restrict__ efsort,
                               u16* __restrict__ lsort) {
    int e = blockIdx.x * 256 + threadIdx.x;
    if (e < N_EDGES) {
        int sn = ei[e];
        int rc = ei[N_EDGES + e];
        float4 ea = *(const float4*)(edge_attrs + (size_t)e * 4);
        float4 f0 = *(const float4*)(edge_feats + (size_t)e * 8);
        float4 f1 = *(const float4*)(edge_feats + (size_t)e * 8 + 4);
        float len = lengths[e];
        uint4 pk;
        pk.x = (u32)f2bf(f0.x) | ((u32)f2bf(f0.y) << 16);
        pk.y = (u32)f2bf(f0.z) | ((u32)f2bf(f0.w) << 16);
        pk.z = (u32)f2bf(f1.x) | ((u32)f2bf(f1.y) << 16);
        pk.w = (u32)f2bf(f1.z) | ((u32)f2bf(f1.w) << 16);
        int pos = atomicAdd(&cursor[rc], 1);
        ssort[pos] = sn;
        rsort[pos] = rc;
        *(float4*)(easort + (size_t)pos * 4) = ea;
        *(uint4*)(efsort + (size_t)pos * 8) = pk;
        lsort[pos] = f2bf(len);
    }
}

// ---- K3: edge MLP. Two LDS buffers, all rows wave-private:
//      mlpbuf = staging (read-only after stage); hbuf = h1 then h2 (wave w's rows
//      [16w,16w+16) written/read only by wave w, in program order) -> race-free,
//      NO barriers; setprio(1) around MFMA clusters. 30.7KB LDS, 5 blocks/CU. ----
__global__ __launch_bounds__(256, 5) void mlp_kernel(
    const u16* __restrict__ ns_bf,
    const u16* __restrict__ W1f, const u16* __restrict__ W2f, const u16* __restrict__ W3f,
    const float* __restrict__ b1, const float* __restrict__ b2,
    const int* __restrict__ ssort, const int* __restrict__ rsort,
    const u16* __restrict__ efsort, const u16* __restrict__ lsort,
    u16* __restrict__ twg) {

    __shared__ u16 mlpbuf[64][168];   // staging only
    __shared__ u16 hbuf[64][72];      // h1, then h2 (row-private reuse)

    const int tid = threadIdx.x;
    const int l = tid & 63;
    const int lo16 = l & 15;
    const int hi = l >> 4;
    const int w = tid >> 6;
    const int erow = (w << 4) | lo16;
    const int koff = hi * 8;
    const int drow = (w << 4) + hi * 4;

    // XCD-aware swizzle: grid 5000 = 8 XCDs x 625 contiguous blocks
    const int nwg = N_EDGES / 64;
    const int cpx = nwg / 8;
    const int bid = (int)blockIdx.x;
    const int swz = (bid % 8) * cpx + bid / 8;
    const int p0 = swz * 64;

    const short8* w1frag = (const short8*)W1f;
    const half8* w2frag = (const half8*)W2f;
    const half8* w3frag = (const half8*)W3f;

    float bb1[4], bb2[4];
#pragma unroll
    for (int jt = 0; jt < 4; jt++) { bb1[jt] = b1[jt * 16 + lo16]; bb2[jt] = b2[jt * 16 + lo16]; }

    // zero pad region k=136..167 (wave-private rows)
    {
        int rr = tid >> 2, pp = tid & 3;
        uint4 z = {0, 0, 0, 0};
        *(uint4*)&mlpbuf[rr][136 + pp * 8] = z;
    }

    // stage gathered edge inputs (wave-private rows)
    {
        int es = tid >> 2, part = tid & 3;
        int sn = ssort[p0 + es];
        int rc = rsort[p0 + es];
        const uint4* ps = (const uint4*)(ns_bf + (size_t)sn * 64 + part * 16);
        uint4 s0 = ps[0], s1 = ps[1];
        *(uint4*)&mlpbuf[es][part * 16] = s0;
        *(uint4*)&mlpbuf[es][part * 16 + 8] = s1;
        const uint4* pr = (const uint4*)(ns_bf + (size_t)rc * 64 + part * 16);
        uint4 r0v = pr[0], r1v = pr[1];
        *(uint4*)&mlpbuf[es][64 + part * 16] = r0v;
        *(uint4*)&mlpbuf[es][64 + part * 16 + 8] = r1v;
        if (part == 0) {
            uint4 pk = *(const uint4*)(efsort + (size_t)(p0 + es) * 8);
            *(uint4*)&mlpbuf[es][128] = pk;
            mlpbuf[es][136] = lsort[p0 + es];
        }
    }
    // no barrier: rows are wave-private; per-wave in-order DS execution suffices

    // layer 1: (64x160) @ (160x64), bf16
    f32x4 a1c[4];
#pragma unroll
    for (int jt = 0; jt < 4; jt++) a1c[jt] = (f32x4)(0.0f);
    __builtin_amdgcn_s_setprio(1);
#pragma unroll
    for (int kk = 0; kk < 5; kk++) {
        short8 af = *(const short8*)&mlpbuf[erow][kk * 32 + koff];
        const short8* wb = w1frag + kk * 256 + l;
        a1c[0] = mfma16(af, wb[0],   a1c[0]);
        a1c[1] = mfma16(af, wb[64],  a1c[1]);
        a1c[2] = mfma16(af, wb[128], a1c[2]);
        a1c[3] = mfma16(af, wb[192], a1c[3]);
    }
    __builtin_amdgcn_s_setprio(0);
    // h1 -> hbuf rows drow..drow+3 (wave-private)
#pragma unroll
    for (int r = 0; r < 4; r++) {
        uint2 pk;
        pk.x = pkh(silu(a1c[0][r] + bb1[0]), silu(a1c[1][r] + bb1[1]));
        pk.y = pkh(silu(a1c[2][r] + bb1[2]), silu(a1c[3][r] + bb1[3]));
        *(uint2*)&hbuf[drow + r][lo16 * 4] = pk;
    }

    // layer 2: (64x64) @ (64x64), fp16 (permuted K); h1 in hbuf
    f32x4 a2c[4];
#pragma unroll
    for (int jt = 0; jt < 4; jt++) a2c[jt] = (f32x4)(0.0f);
    __builtin_amdgcn_s_setprio(1);
#pragma unroll
    for (int kk = 0; kk < 2; kk++) {
        half8 af = *(const half8*)&hbuf[erow][kk * 32 + koff];
        const half8* wb = w2frag + kk * 256 + l;
        a2c[0] = mfma16h(af, wb[0],   a2c[0]);
        a2c[1] = mfma16h(af, wb[64],  a2c[1]);
        a2c[2] = mfma16h(af, wb[128], a2c[2]);
        a2c[3] = mfma16h(af, wb[192], a2c[3]);
    }
    __builtin_amdgcn_s_setprio(0);
    // h2 overwrites h1 in hbuf (same wave's rows; its L2 reads of those rows are done)
#pragma unroll
    for (int r = 0; r < 4; r++) {
        uint2 pk;
        pk.x = pkh(silu(a2c[0][r] + bb2[0]), silu(a2c[1][r] + bb2[1]));
        pk.y = pkh(silu(a2c[2][r] + bb2[2]), silu(a2c[3][r] + bb2[3]));
        *(uint2*)&hbuf[drow + r][lo16 * 4] = pk;
    }

    // layer 3: (64x64) @ (64x256), fp16 (permuted K); h2 in hbuf
    f32x4 tw[16];
#pragma unroll
    for (int jt = 0; jt < 16; jt++) tw[jt] = (f32x4)(0.0f);
    __builtin_amdgcn_s_setprio(1);
#pragma unroll
    for (int kk = 0; kk < 2; kk++) {
        half8 af = *(const half8*)&hbuf[erow][kk * 32 + koff];
        const half8* wb = w3frag + kk * 1024 + l;
#pragma unroll
        for (int jt = 0; jt < 16; jt++) tw[jt] = mfma16h(af, wb[jt * 64], tw[jt]);
    }
    __builtin_amdgcn_s_setprio(0);

    // store tw channel-major: tw[jt] -> q = jt>>2, c = (jt&3)*16+lo16; twg[e*256 + c*4 + q]
    int relrow = p0 + drow;
#pragma unroll
    for (int r = 0; r < 4; r++) {
        u16* dst = twg + (size_t)(relrow + r) * 256 + lo16 * 4;
#pragma unroll
        for (int jt4 = 0; jt4 < 4; jt4++) {
            uint2 pk;
            pk.x = pkh(tw[jt4][r],     tw[4 + jt4][r]);
            pk.y = pkh(tw[8 + jt4][r], tw[12 + jt4][r]);
            *(uint2*)(dst + jt4 * 64) = pk;
        }
    }
}

// ---- K4: one wave per node; tensor products + register segment-sum;
//      channel-major tw; XCD-swizzled blockIdx; no LDS -> 6 blocks/CU for latency hiding ----
__global__ __launch_bounds__(256, 6) void seg_kernel(
    const u16* __restrict__ svh, const float* __restrict__ easort,
    const int* __restrict__ ssort,
    const int* __restrict__ offs, const u16* __restrict__ twg,
    float* __restrict__ m_g) {
    const int lane = threadIdx.x & 63;
    const int wv = threadIdx.x >> 6;
    const int nwg = N_NODES / 4;
    const int cpx = nwg / 8;
    const int bid = (int)blockIdx.x;
    const int swz = (bid % 8) * cpx + bid / 8;
    const int n = swz * 4 + wv;
    const int c = lane;
    const int e0 = offs[n], e1 = offs[n + 1];
    float a_m0 = 0.f, a_m0b = 0.f;
    float a20 = 0.f, a21 = 0.f, a22 = 0.f, a30 = 0.f, a31 = 0.f, a32 = 0.f;
#pragma unroll 4
    for (int pos = e0; pos < e1; ++pos) {
        int sn = ssort[pos];
        uint2 tq = *(const uint2*)(twg + (size_t)pos * 256 + c * 4);
        f32x4 y4 = *(const f32x4*)(easort + (size_t)pos * 4);
        uint2 sp = *(const uint2*)&svh[((size_t)sn * 64 + c) * 4];
        float w0 = h2f(tq.x & 0xffffu);
        float w1 = h2f(tq.x >> 16);
        float w2 = h2f(tq.y & 0xffffu);
        float w3 = h2f(tq.y >> 16);
        float xs  = h2f(sp.x & 0xffffu);
        float xv0 = h2f(sp.x >> 16);
        float xv1 = h2f(sp.y & 0xffffu);
        float xv2 = h2f(sp.y >> 16);
        float y0 = y4.x, ya = y4.y, yb = y4.z, yc = y4.w;
        a_m0 = fmaf(xs * y0, w0, a_m0);
        float dv = xv0 * ya + xv1 * yb + xv2 * yc;
        a_m0b = fmaf(dv, w1, a_m0b);
        float sw2 = xs * w2;
        a20 = fmaf(sw2, ya, a20); a21 = fmaf(sw2, yb, a21); a22 = fmaf(sw2, yc, a22);
        float yw3 = y0 * w3;
        a30 = fmaf(xv0, yw3, a30); a31 = fmaf(xv1, yw3, a31); a32 = fmaf(xv2, yw3, a32);
    }
    float* mr = m_g + (size_t)n * 512;
    ntstore(mr + c,        a_m0);
    ntstore(mr + 64 + c,   a_m0b * INV_SQRT3);
    ntstore(mr + 128 + c,  a20);
    ntstore(mr + 192 + c,  a30);
    ntstore(mr + 256 + c,  a21);
    ntstore(mr + 320 + c,  a31);
    ntstore(mr + 384 + c,  a22);
    ntstore(mr + 448 + c,  a32);
}

// ---- K5: MFMA epilogue. 64 nodes/block, 4 waves, no LDS, no barriers. ----
__global__ __launch_bounds__(256, 2) void out_kernel(
    const float* __restrict__ m_g, const u16* __restrict__ WSF,
    float* __restrict__ out) {
    const int tid = threadIdx.x;
    const int lane = tid & 63;
    const int w = tid >> 6;
    const int lo16 = lane & 15;
    const int hi = lane >> 4;
    const int nb = blockIdx.x * 64 + w * 16;

    int arow_n = nb + lo16;
    if (arow_n > N_NODES - 1) arow_n = N_NODES - 1;
    const float* arow = m_g + (size_t)arow_n * 512 + hi * 8;

    const short8* bsh = (const short8*)WSF;
    const short8* bsl = (const short8*)(WSF + 8192);
    const short8* bvh = (const short8*)(WSF + 16384);
    const short8* bvl = (const short8*)(WSF + 24576);

    f32x4 acc[4][4];
#pragma unroll
    for (int q = 0; q < 4; q++)
#pragma unroll
        for (int jt = 0; jt < 4; jt++) acc[q][jt] = (f32x4)(0.0f);

#pragma unroll
    for (int kk = 0; kk < 4; kk++) {
        short8 ahi[4], alo[4];
#pragma unroll
        for (int q = 0; q < 4; q++) {
            const float* p = arow + q * 128 + kk * 32;
            f32x4 x0 = ntload((const f32x4*)p);
            f32x4 x1 = ntload((const f32x4*)(p + 4));
#pragma unroll
            for (int j = 0; j < 4; j++) {
                u16 h0 = f2bf(x0[j]);
                ahi[q][j] = (short)h0;
                alo[q][j] = (short)f2bf(x0[j] - bf2f(h0));
                u16 h1 = f2bf(x1[j]);
                ahi[q][4 + j] = (short)h1;
                alo[q][4 + j] = (short)f2bf(x1[j] - bf2f(h1));
            }
        }
#pragma unroll
        for (int jt = 0; jt < 4; jt++) {
            int bidx = (kk * 4 + jt) * 64 + lane;
            short8 wh_s = bsh[bidx];
            short8 wl_s = bsl[bidx];
            short8 wh_v = bvh[bidx];
            short8 wl_v = bvl[bidx];
            acc[0][jt] = mfma16(ahi[0], wh_s, acc[0][jt]);
            acc[0][jt] = mfma16(alo[0], wh_s, acc[0][jt]);
            acc[0][jt] = mfma16(ahi[0], wl_s, acc[0][jt]);
#pragma unroll
            for (int q = 1; q < 4; q++) {
                acc[q][jt] = mfma16(ahi[q], wh_v, acc[q][jt]);
                acc[q][jt] = mfma16(alo[q], wh_v, acc[q][jt]);
                acc[q][jt] = mfma16(ahi[q], wl_v, acc[q][jt]);
            }
        }
    }

#pragma unroll
    for (int r = 0; r < 4; r++) {
        int n = nb + hi * 4 + r;
        if (n < N_NODES) {
#pragma unroll
            for (int jt = 0; jt < 4; jt++) {
                int d = jt * 16 + lo16;
                f32x4 o;
                o.x = acc[0][jt][r] * 0.0625f;
                o.y = acc[1][jt][r] * 0.0625f;
                o.z = acc[2][jt][r] * 0.0625f;
                o.w = acc[3][jt][r] * 0.0625f;
                ntstore((f32x4*)(out + (size_t)n * 256 + d * 4), o);
            }
        }
    }
}

extern "C" void kernel_launch(void* const* d_in, const int* in_sizes, int n_in,
                              void* d_out, int out_size, void* d_ws, size_t ws_size,
                              hipStream_t stream) {
    (void)in_sizes; (void)n_in; (void)out_size; (void)ws_size;
    const float* node_feats = (const float*)d_in[0];
    const float* edge_attrs = (const float*)d_in[1];
    const float* edge_feats = (const float*)d_in[2];
    const float* lengths    = (const float*)d_in[3];
    const int*   edge_index = (const int*)d_in[4];
    const float* Wsc  = (const float*)d_in[5];
    const float* Wup0 = (const float*)d_in[6];
    const float* Wup1 = (const float*)d_in[7];
    const float* W1   = (const float*)d_in[8];
    const float* b1   = (const float*)d_in[9];
    const float* W2   = (const float*)d_in[10];
    const float* b2   = (const float*)d_in[11];
    const float* W3   = (const float*)d_in[12];
    const float* Ws   = (const float*)d_in[13];
    const float* Wv   = (const float*)d_in[14];

    char* ws = (char*)d_ws;
    u16*   ns_bf  = (u16*)(ws + OFF_NSBF);
    u16*   svh    = (u16*)(ws + OFF_SV);
    float* m_g    = (float*)(ws + OFF_MG);
    u16*   twg    = (u16*)(ws + OFF_TW);
    u16*   W1f    = (u16*)(ws + OFF_W1F);
    u16*   W2f    = (u16*)(ws + OFF_W2F);
    u16*   W3f    = (u16*)(ws + OFF_W3F);
    u16*   WNF    = (u16*)(ws + OFF_WNF);
    int*   cnt    = (int*)(ws + OFF_CNT);
    int*   offs   = (int*)(ws + OFF_OFFS);
    int*   cursor = (int*)(ws + OFF_CUR);
    u16*   WSF    = (u16*)(ws + OFF_WSF);
    int*   ssort  = (int*)(ws + OFF_SS);
    int*   rsort  = (int*)(ws + OFF_RS);
    float* easort = (float*)(ws + OFF_EA);
    u16*   efsort = (u16*)(ws + OFF_EF);
    u16*   lsort  = (u16*)(ws + OFF_LEN);
    float* out    = (float*)d_out;

    (void)hipMemsetAsync(cnt, 0, N_NODES * sizeof(int), stream);
    prep_all_kernel<<<29, 256, 0, stream>>>(W1, W2, W3, Wsc, Wup0, Wup1, Ws, Wv,
                                            W1f, W2f, W3f, WNF, WSF);
    node_prep_kernel<<<(N_NODES + 63) / 64, 256, 0, stream>>>(node_feats, WNF, ns_bf, svh);
    hist_kernel<<<N_EDGES / 256, 256, 0, stream>>>(edge_index, cnt);
    scan_kernel<<<1, 1024, 0, stream>>>(cnt, offs, cursor);
    scatter_kernel<<<N_EDGES / 256, 256, 0, stream>>>(edge_index, edge_attrs, edge_feats,
                                                      lengths, cursor,
                                                      ssort, rsort, easort, efsort, lsort);

    mlp_kernel<<<N_EDGES / 64, 256, 0, stream>>>(ns_bf, W1f, W2f, W3f, b1, b2,
                                                 ssort, rsort, efsort, lsort, twg);
    seg_kernel<<<N_NODES / 4, 256, 0, stream>>>(svh, easort, ssort,
                                                offs, twg, m_g);
    out_kernel<<<(N_NODES + 63) / 64, 256, 0, stream>>>(m_g, WSF, out);
}

// Round 22
// 219.266 us; speedup vs baseline: 1.2186x; 1.0396x over previous
//
#include <hip/hip_runtime.h>

#define N_NODES 20000
#define N_EDGES 320000
#define INV_SQRT3 0.5773502691896258f

typedef unsigned short u16;
typedef unsigned int u32;
typedef __attribute__((ext_vector_type(8))) short short8;
typedef __attribute__((ext_vector_type(8))) _Float16 half8;
typedef __attribute__((ext_vector_type(2))) __fp16 fp16x2;
typedef __attribute__((ext_vector_type(4))) float f32x4;
typedef __attribute__((ext_vector_type(4))) u32 u32x4v;

// ---- workspace layout (bytes), ws = 256 MiB ----
static const size_t OFF_NSBF = 0;            // N*64 bf16
static const size_t OFF_SV   = 2560000;      // N*64 * 4 fp16 (8B/ch)
static const size_t OFF_MG   = 23040000;     // N*512 fp16 (20.5MB)
static const size_t OFF_TW   = 64000000;     // E*256 fp16, channel-major [c*4+q]
static const size_t OFF_W1F  = 227840000;    // 20480
static const size_t OFF_W2F  = 227860480;    // 8192
static const size_t OFF_W3F  = 227868672;    // 32768
static const size_t OFF_WNF  = 227901440;    // 49152
static const size_t OFF_CNT  = 227950592;    // 80000
static const size_t OFF_OFFS = 228030592;    // 80016
static const size_t OFF_CUR  = 228110608;    // 80000 (cursor only)
static const size_t OFF_SS   = 229470608;    // 1,280,000
static const size_t OFF_RS   = 230750608;    // 1,280,000
static const size_t OFF_EA   = 232030608;    // E*16B easort
static const size_t OFF_EF   = 237150608;    // E*16B efsort (8 bf16)
static const size_t OFF_LEN  = 242270608;    // E*2B lsort
static const size_t OFF_WSF  = 243550608;    // 64KB Ws/Wv hi-lo frags -> ends 243,616,144

static __device__ __forceinline__ u16 f2bf(float x) {
    union { float f; u32 u; } c; c.f = x;
    u32 u = c.u + 0x7fffu + ((c.u >> 16) & 1u);
    return (u16)(u >> 16);
}
static __device__ __forceinline__ float bf2f(u16 b) {
    union { u32 u; float f; } c; c.u = (u32)b << 16; return c.f;
}
static __device__ __forceinline__ u16 f2h(float x) {
    union { _Float16 h; u16 u; } c; c.h = (_Float16)x; return c.u;
}
static __device__ __forceinline__ float h2f(u32 b) {
    union { u16 u; _Float16 h; } c; c.u = (u16)b; return (float)c.h;
}
static __device__ __forceinline__ u32 pkh(float a, float b) {
    union { fp16x2 h; u32 u; } c;
    c.h = __builtin_amdgcn_cvt_pkrtz(a, b);
    return c.u;
}
static __device__ __forceinline__ f32x4 mfma16(short8 a, short8 b, f32x4 c) {
    return __builtin_amdgcn_mfma_f32_16x16x32_bf16(a, b, c, 0, 0, 0);
}
static __device__ __forceinline__ f32x4 mfma16h(half8 a, half8 b, f32x4 c) {
    return __builtin_amdgcn_mfma_f32_16x16x32_f16(a, b, c, 0, 0, 0);
}
static __device__ __forceinline__ float silu(float x) {
    return x / (1.0f + __expf(-x));
}
template <typename T>
static __device__ __forceinline__ T ntload(const T* p) { return __builtin_nontemporal_load(p); }
template <typename T>
static __device__ __forceinline__ void ntstore(T* p, T v) { __builtin_nontemporal_store(v, p); }

// ---- merged weight prep: W1/W2/W3 frags + Wsc/Wup frags + Ws/Wv hi-lo frags ----
__global__ void prep_all_kernel(const float* __restrict__ W1, const float* __restrict__ W2,
                                const float* __restrict__ W3,
                                const float* __restrict__ Wsc, const float* __restrict__ Wup0,
                                const float* __restrict__ Wup1,
                                const float* __restrict__ Ws, const float* __restrict__ Wv,
                                u16* __restrict__ W1f, u16* __restrict__ W2f,
                                u16* __restrict__ W3f, u16* __restrict__ WNF,
                                u16* __restrict__ WSF) {
    int t = blockIdx.x * 256 + threadIdx.x;
    if (t < 3840) {
        int l = t & 63, grp = t >> 6;
        int hi = l >> 4, lo = l & 15;
        if (grp < 20) {
            int kk = grp >> 2, jt = grp & 3;
#pragma unroll
            for (int e2 = 0; e2 < 8; e2++) {
                int k = kk * 32 + hi * 8 + e2, j = jt * 16 + lo;
                W1f[(size_t)(grp * 64 + l) * 8 + e2] = (k < 137) ? f2bf(W1[k * 64 + j]) : (u16)0;
            }
        } else if (grp < 28) {
            int g = grp - 20; int kk = g >> 2, jt = g & 3;
#pragma unroll
            for (int e2 = 0; e2 < 8; e2++) {
                int k = kk * 32 + hi * 8 + e2, j = jt * 16 + lo;
                int kp = ((k & 3) << 4) + (k >> 2);
                W2f[(size_t)(g * 64 + l) * 8 + e2] = f2h(W2[kp * 64 + j]);
            }
        } else {
            int g = grp - 28; int kk = g >> 4, jt = g & 15;
#pragma unroll
            for (int e2 = 0; e2 < 8; e2++) {
                int k = kk * 32 + hi * 8 + e2, j = jt * 16 + lo;
                int kp = ((k & 3) << 4) + (k >> 2);
                W3f[(size_t)(g * 64 + l) * 8 + e2] = f2h(W3[kp * 256 + j]);
            }
        }
    } else if (t < 5376) {
        int tt = t - 3840;
        int mat = tt >> 9;
        int rem = tt & 511;
        int g = rem >> 6, l = rem & 63;
        int kk = g >> 2, jt = g & 3, hi = l >> 4, lo = l & 15;
        const float* W = (mat == 0) ? Wsc : (mat == 1) ? Wup0 : Wup1;
        u16* dh = WNF + (size_t)mat * 8192 + (size_t)(g * 64 + l) * 8;
        u16* dl = dh + 4096;
#pragma unroll
        for (int e2 = 0; e2 < 8; e2++) {
            int k = kk * 32 + hi * 8 + e2, d = jt * 16 + lo;
            float w = W[k * 64 + d];
            u16 h = f2bf(w);
            dh[e2] = h;
            dl[e2] = f2bf(w - bf2f(h));
        }
    } else if (t < 7424) {
        int tt = t - 5376;
        int l = tt & 63, grp = tt >> 6;
        int wsel = grp >> 4;
        int g = grp & 15;
        int kk = g >> 2, jt = g & 3;
        int hi = l >> 4, lo = l & 15;
        const float* W = wsel ? Wv : Ws;
        u16* dh = WSF + (size_t)wsel * 16384;
        u16* dl = dh + 8192;
        size_t base = (size_t)(g * 64 + l) * 8;
#pragma unroll
        for (int e2 = 0; e2 < 8; e2++) {
            int k = kk * 32 + hi * 8 + e2, d = jt * 16 + lo;
            float w = W[k * 64 + d];
            u16 h = f2bf(w);
            float r = w - bf2f(h);
            dh[base + e2] = h;
            dl[base + e2] = f2bf(r);
        }
    }
}

// ---- node precompute: MFMA, hi/lo split A; sv output packed fp16 ----
__global__ __launch_bounds__(256) void node_prep_kernel(
    const float* __restrict__ node_feats, const u16* __restrict__ WNF,
    u16* __restrict__ ns_bf, u16* __restrict__ svh) {
    const int tid = threadIdx.x;
    const int lane = tid & 63;
    const int w = tid >> 6;
    const int lo16 = lane & 15;
    const int hi = lane >> 4;
    const int nb = blockIdx.x * 64 + w * 16;

    int an = nb + lo16; if (an > N_NODES - 1) an = N_NODES - 1;
    const float* arow = node_feats + (size_t)an * 256;

    const short8* B = (const short8*)WNF;

    f32x4 acc_ns[4], acc_su[4], acc_v[3][4];
#pragma unroll
    for (int jt = 0; jt < 4; jt++) {
        acc_ns[jt] = (f32x4)(0.0f);
        acc_su[jt] = (f32x4)(0.0f);
#pragma unroll
        for (int i = 0; i < 3; i++) acc_v[i][jt] = (f32x4)(0.0f);
    }

#pragma unroll
    for (int kk = 0; kk < 2; kk++) {
        short8 sh, sl;
        {
            const float* sp = arow + kk * 32 + hi * 8;
            f32x4 x0 = *(const f32x4*)sp;
            f32x4 x1 = *(const f32x4*)(sp + 4);
#pragma unroll
            for (int j = 0; j < 4; j++) {
                u16 h0 = f2bf(x0[j]);
                sh[j] = (short)h0;
                sl[j] = (short)f2bf(x0[j] - bf2f(h0));
                u16 h1 = f2bf(x1[j]);
                sh[4 + j] = (short)h1;
                sl[4 + j] = (short)f2bf(x1[j] - bf2f(h1));
            }
        }
        short8 vh[3], vl[3];
#pragma unroll
        for (int i = 0; i < 3; i++) {
            const float* vp = arow + 64 + i + 3 * (kk * 32 + hi * 8);
#pragma unroll
            for (int e = 0; e < 8; e++) {
                float x = vp[e * 3];
                u16 hb = f2bf(x);
                vh[i][e] = (short)hb;
                vl[i][e] = (short)f2bf(x - bf2f(hb));
            }
        }
#pragma unroll
        for (int jt = 0; jt < 4; jt++) {
            int fi = (kk * 4 + jt) * 64 + lane;
            short8 bh = B[fi], bl = B[512 + fi];
            acc_ns[jt] = mfma16(sh, bh, acc_ns[jt]);
            acc_ns[jt] = mfma16(sl, bh, acc_ns[jt]);
            acc_ns[jt] = mfma16(sh, bl, acc_ns[jt]);
            bh = B[1024 + fi]; bl = B[1536 + fi];
            acc_su[jt] = mfma16(sh, bh, acc_su[jt]);
            acc_su[jt] = mfma16(sl, bh, acc_su[jt]);
            acc_su[jt] = mfma16(sh, bl, acc_su[jt]);
            bh = B[2048 + fi]; bl = B[2560 + fi];
#pragma unroll
            for (int i = 0; i < 3; i++) {
                acc_v[i][jt] = mfma16(vh[i], bh, acc_v[i][jt]);
                acc_v[i][jt] = mfma16(vl[i], bh, acc_v[i][jt]);
                acc_v[i][jt] = mfma16(vh[i], bl, acc_v[i][jt]);
            }
        }
    }

#pragma unroll
    for (int r = 0; r < 4; r++) {
        int n = nb + hi * 4 + r;
        if (n < N_NODES) {
#pragma unroll
            for (int jt = 0; jt < 4; jt++) {
                int d = jt * 16 + lo16;
                ns_bf[(size_t)n * 64 + d] = f2bf(acc_ns[jt][r]);
                uint2 o;
                o.x = pkh(acc_su[jt][r], acc_v[0][jt][r]);
                o.y = pkh(acc_v[1][jt][r], acc_v[2][jt][r]);
                *(uint2*)&svh[((size_t)n * 64 + d) * 4] = o;
            }
        }
    }
}

// ---- counting sort by rcv ----
__global__ void hist_kernel(const int* __restrict__ ei, int* __restrict__ cnt) {
    int e = blockIdx.x * 256 + threadIdx.x;
    if (e < N_EDGES) atomicAdd(&cnt[ei[N_EDGES + e]], 1);
}

__global__ void scan_kernel(const int* __restrict__ cnt, int* __restrict__ offs,
                            int* __restrict__ cursor) {
    __shared__ int buf[1024];
    int t = threadIdx.x;
    int base = t * 20;
    int loc[20];
    int tot = 0;
    int v20[20];
    if (base < N_NODES) {
#pragma unroll
        for (int q = 0; q < 5; q++) {
            int4 vv = *(const int4*)&cnt[base + q * 4];
            v20[q * 4 + 0] = vv.x; v20[q * 4 + 1] = vv.y;
            v20[q * 4 + 2] = vv.z; v20[q * 4 + 3] = vv.w;
        }
    } else {
#pragma unroll
        for (int i = 0; i < 20; i++) v20[i] = 0;
    }
#pragma unroll
    for (int i = 0; i < 20; i++) { loc[i] = tot; tot += v20[i]; }
    buf[t] = tot;
    __syncthreads();
    for (int d = 1; d < 1024; d <<= 1) {
        int add = (t >= d) ? buf[t - d] : 0;
        __syncthreads();
        buf[t] += add;
        __syncthreads();
    }
    int ebase = buf[t] - tot;
#pragma unroll
    for (int i = 0; i < 20; i++) {
        int idx = base + i;
        if (idx < N_NODES) { int o = ebase + loc[i]; offs[idx] = o; cursor[idx] = o; }
    }
    if (t == 1023) offs[N_NODES] = buf[1023];
}

// ---- scatter: sort + pre-gather edge payloads into sorted order ----
__global__ void scatter_kernel(const int* __restrict__ ei, const float* __restrict__ edge_attrs,
                               const float* __restrict__ edge_feats, const float* __restrict__ lengths,
                               int* __restrict__ cursor,
                               int* __restrict__ ssort, int* __restrict__ rsort,
                               float* __restrict__ easort, u16* __restrict__ efsort,
                               u16* __restrict__ lsort) {
    int e = blockIdx.x * 256 + threadIdx.x;
    if (e < N_EDGES) {
        int sn = ei[e];
        int rc = ei[N_EDGES + e];
        float4 ea = *(const float4*)(edge_attrs + (size_t)e * 4);
        float4 f0 = *(const float4*)(edge_feats + (size_t)e * 8);
        float4 f1 = *(const float4*)(edge_feats + (size_t)e * 8 + 4);
        float len = lengths[e];
        uint4 pk;
        pk.x = (u32)f2bf(f0.x) | ((u32)f2bf(f0.y) << 16);
        pk.y = (u32)f2bf(f0.z) | ((u32)f2bf(f0.w) << 16);
        pk.z = (u32)f2bf(f1.x) | ((u32)f2bf(f1.y) << 16);
        pk.w = (u32)f2bf(f1.z) | ((u32)f2bf(f1.w) << 16);
        int pos = atomicAdd(&cursor[rc], 1);
        ssort[pos] = sn;
        rsort[pos] = rc;
        *(float4*)(easort + (size_t)pos * 4) = ea;
        *(uint4*)(efsort + (size_t)pos * 8) = pk;
        lsort[pos] = f2bf(len);
    }
}

// ---- K3: edge MLP. Two LDS buffers, all rows wave-private:
//      mlpbuf = staging (read-only after stage); hbuf = h1 then h2 (wave w's rows
//      [16w,16w+16) written/read only by wave w, in program order) -> race-free,
//      NO barriers; setprio(1) around MFMA clusters. 30.7KB LDS, 5 blocks/CU. ----
__global__ __launch_bounds__(256, 5) void mlp_kernel(
    const u16* __restrict__ ns_bf,
    const u16* __restrict__ W1f, const u16* __restrict__ W2f, const u16* __restrict__ W3f,
    const float* __restrict__ b1, const float* __restrict__ b2,
    const int* __restrict__ ssort, const int* __restrict__ rsort,
    const u16* __restrict__ efsort, const u16* __restrict__ lsort,
    u16* __restrict__ twg) {

    __shared__ u16 mlpbuf[64][168];   // staging only
    __shared__ u16 hbuf[64][72];      // h1, then h2 (row-private reuse)

    const int tid = threadIdx.x;
    const int l = tid & 63;
    const int lo16 = l & 15;
    const int hi = l >> 4;
    const int w = tid >> 6;
    const int erow = (w << 4) | lo16;
    const int koff = hi * 8;
    const int drow = (w << 4) + hi * 4;

    // XCD-aware swizzle: grid 5000 = 8 XCDs x 625 contiguous blocks
    const int nwg = N_EDGES / 64;
    const int cpx = nwg / 8;
    const int bid = (int)blockIdx.x;
    const int swz = (bid % 8) * cpx + bid / 8;
    const int p0 = swz * 64;

    const short8* w1frag = (const short8*)W1f;
    const half8* w2frag = (const half8*)W2f;
    const half8* w3frag = (const half8*)W3f;

    float bb1[4], bb2[4];
#pragma unroll
    for (int jt = 0; jt < 4; jt++) { bb1[jt] = b1[jt * 16 + lo16]; bb2[jt] = b2[jt * 16 + lo16]; }

    // zero pad region k=136..167 (wave-private rows)
    {
        int rr = tid >> 2, pp = tid & 3;
        uint4 z = {0, 0, 0, 0};
        *(uint4*)&mlpbuf[rr][136 + pp * 8] = z;
    }

    // stage gathered edge inputs (wave-private rows)
    {
        int es = tid >> 2, part = tid & 3;
        int sn = ssort[p0 + es];
        int rc = rsort[p0 + es];
        const uint4* ps = (const uint4*)(ns_bf + (size_t)sn * 64 + part * 16);
        uint4 s0 = ps[0], s1 = ps[1];
        *(uint4*)&mlpbuf[es][part * 16] = s0;
        *(uint4*)&mlpbuf[es][part * 16 + 8] = s1;
        const uint4* pr = (const uint4*)(ns_bf + (size_t)rc * 64 + part * 16);
        uint4 r0v = pr[0], r1v = pr[1];
        *(uint4*)&mlpbuf[es][64 + part * 16] = r0v;
        *(uint4*)&mlpbuf[es][64 + part * 16 + 8] = r1v;
        if (part == 0) {
            uint4 pk = *(const uint4*)(efsort + (size_t)(p0 + es) * 8);
            *(uint4*)&mlpbuf[es][128] = pk;
            mlpbuf[es][136] = lsort[p0 + es];
        }
    }
    // no barrier: rows are wave-private; per-wave in-order DS execution suffices

    // layer 1: (64x160) @ (160x64), bf16
    f32x4 a1c[4];
#pragma unroll
    for (int jt = 0; jt < 4; jt++) a1c[jt] = (f32x4)(0.0f);
    __builtin_amdgcn_s_setprio(1);
#pragma unroll
    for (int kk = 0; kk < 5; kk++) {
        short8 af = *(const short8*)&mlpbuf[erow][kk * 32 + koff];
        const short8* wb = w1frag + kk * 256 + l;
        a1c[0] = mfma16(af, wb[0],   a1c[0]);
        a1c[1] = mfma16(af, wb[64],  a1c[1]);
        a1c[2] = mfma16(af, wb[128], a1c[2]);
        a1c[3] = mfma16(af, wb[192], a1c[3]);
    }
    __builtin_amdgcn_s_setprio(0);
    // h1 -> hbuf rows drow..drow+3 (wave-private)
#pragma unroll
    for (int r = 0; r < 4; r++) {
        uint2 pk;
        pk.x = pkh(silu(a1c[0][r] + bb1[0]), silu(a1c[1][r] + bb1[1]));
        pk.y = pkh(silu(a1c[2][r] + bb1[2]), silu(a1c[3][r] + bb1[3]));
        *(uint2*)&hbuf[drow + r][lo16 * 4] = pk;
    }

    // layer 2: (64x64) @ (64x64), fp16 (permuted K); h1 in hbuf
    f32x4 a2c[4];
#pragma unroll
    for (int jt = 0; jt < 4; jt++) a2c[jt] = (f32x4)(0.0f);
    __builtin_amdgcn_s_setprio(1);
#pragma unroll
    for (int kk = 0; kk < 2; kk++) {
        half8 af = *(const half8*)&hbuf[erow][kk * 32 + koff];
        const half8* wb = w2frag + kk * 256 + l;
        a2c[0] = mfma16h(af, wb[0],   a2c[0]);
        a2c[1] = mfma16h(af, wb[64],  a2c[1]);
        a2c[2] = mfma16h(af, wb[128], a2c[2]);
        a2c[3] = mfma16h(af, wb[192], a2c[3]);
    }
    __builtin_amdgcn_s_setprio(0);
    // h2 overwrites h1 in hbuf (same wave's rows; its L2 reads of those rows are done)
#pragma unroll
    for (int r = 0; r < 4; r++) {
        uint2 pk;
        pk.x = pkh(silu(a2c[0][r] + bb2[0]), silu(a2c[1][r] + bb2[1]));
        pk.y = pkh(silu(a2c[2][r] + bb2[2]), silu(a2c[3][r] + bb2[3]));
        *(uint2*)&hbuf[drow + r][lo16 * 4] = pk;
    }

    // layer 3: (64x64) @ (64x256), fp16 (permuted K); h2 in hbuf
    f32x4 tw[16];
#pragma unroll
    for (int jt = 0; jt < 16; jt++) tw[jt] = (f32x4)(0.0f);
    __builtin_amdgcn_s_setprio(1);
#pragma unroll
    for (int kk = 0; kk < 2; kk++) {
        half8 af = *(const half8*)&hbuf[erow][kk * 32 + koff];
        const half8* wb = w3frag + kk * 1024 + l;
#pragma unroll
        for (int jt = 0; jt < 16; jt++) tw[jt] = mfma16h(af, wb[jt * 64], tw[jt]);
    }
    __builtin_amdgcn_s_setprio(0);

    // store tw channel-major: tw[jt] -> q = jt>>2, c = (jt&3)*16+lo16; twg[e*256 + c*4 + q]
    int relrow = p0 + drow;
#pragma unroll
    for (int r = 0; r < 4; r++) {
        u16* dst = twg + (size_t)(relrow + r) * 256 + lo16 * 4;
#pragma unroll
        for (int jt4 = 0; jt4 < 4; jt4++) {
            uint2 pk;
            pk.x = pkh(tw[jt4][r],     tw[4 + jt4][r]);
            pk.y = pkh(tw[8 + jt4][r], tw[12 + jt4][r]);
            *(uint2*)(dst + jt4 * 64) = pk;
        }
    }
}

// ---- K4: one wave per node; tensor products + register segment-sum;
//      channel-major tw; XCD-swizzled blockIdx; m output stored fp16 ----
__global__ __launch_bounds__(256, 6) void seg_kernel(
    const u16* __restrict__ svh, const float* __restrict__ easort,
    const int* __restrict__ ssort,
    const int* __restrict__ offs, const u16* __restrict__ twg,
    u16* __restrict__ m_gh) {
    const int lane = threadIdx.x & 63;
    const int wv = threadIdx.x >> 6;
    const int nwg = N_NODES / 4;
    const int cpx = nwg / 8;
    const int bid = (int)blockIdx.x;
    const int swz = (bid % 8) * cpx + bid / 8;
    const int n = swz * 4 + wv;
    const int c = lane;
    const int e0 = offs[n], e1 = offs[n + 1];
    float a_m0 = 0.f, a_m0b = 0.f;
    float a20 = 0.f, a21 = 0.f, a22 = 0.f, a30 = 0.f, a31 = 0.f, a32 = 0.f;
#pragma unroll 4
    for (int pos = e0; pos < e1; ++pos) {
        int sn = ssort[pos];
        uint2 tq = *(const uint2*)(twg + (size_t)pos * 256 + c * 4);
        f32x4 y4 = *(const f32x4*)(easort + (size_t)pos * 4);
        uint2 sp = *(const uint2*)&svh[((size_t)sn * 64 + c) * 4];
        float w0 = h2f(tq.x & 0xffffu);
        float w1 = h2f(tq.x >> 16);
        float w2 = h2f(tq.y & 0xffffu);
        float w3 = h2f(tq.y >> 16);
        float xs  = h2f(sp.x & 0xffffu);
        float xv0 = h2f(sp.x >> 16);
        float xv1 = h2f(sp.y & 0xffffu);
        float xv2 = h2f(sp.y >> 16);
        float y0 = y4.x, ya = y4.y, yb = y4.z, yc = y4.w;
        a_m0 = fmaf(xs * y0, w0, a_m0);
        float dv = xv0 * ya + xv1 * yb + xv2 * yc;
        a_m0b = fmaf(dv, w1, a_m0b);
        float sw2 = xs * w2;
        a20 = fmaf(sw2, ya, a20); a21 = fmaf(sw2, yb, a21); a22 = fmaf(sw2, yc, a22);
        float yw3 = y0 * w3;
        a30 = fmaf(xv0, yw3, a30); a31 = fmaf(xv1, yw3, a31); a32 = fmaf(xv2, yw3, a32);
    }
    u16* mr = m_gh + (size_t)n * 512;
    ntstore(mr + c,        f2h(a_m0));
    ntstore(mr + 64 + c,   f2h(a_m0b * INV_SQRT3));
    ntstore(mr + 128 + c,  f2h(a20));
    ntstore(mr + 192 + c,  f2h(a30));
    ntstore(mr + 256 + c,  f2h(a21));
    ntstore(mr + 320 + c,  f2h(a31));
    ntstore(mr + 384 + c,  f2h(a22));
    ntstore(mr + 448 + c,  f2h(a32));
}

// ---- K5: MFMA epilogue. 64 nodes/block, 4 waves, no LDS, no barriers.
//      m read as fp16 (hi/lo bf16 split of fp16 is exact). ----
__global__ __launch_bounds__(256, 2) void out_kernel(
    const u16* __restrict__ m_gh, const u16* __restrict__ WSF,
    float* __restrict__ out) {
    const int tid = threadIdx.x;
    const int lane = tid & 63;
    const int w = tid >> 6;
    const int lo16 = lane & 15;
    const int hi = lane >> 4;
    const int nb = blockIdx.x * 64 + w * 16;

    int arow_n = nb + lo16;
    if (arow_n > N_NODES - 1) arow_n = N_NODES - 1;
    const u16* arow = m_gh + (size_t)arow_n * 512 + hi * 8;

    const short8* bsh = (const short8*)WSF;
    const short8* bsl = (const short8*)(WSF + 8192);
    const short8* bvh = (const short8*)(WSF + 16384);
    const short8* bvl = (const short8*)(WSF + 24576);

    f32x4 acc[4][4];
#pragma unroll
    for (int q = 0; q < 4; q++)
#pragma unroll
        for (int jt = 0; jt < 4; jt++) acc[q][jt] = (f32x4)(0.0f);

#pragma unroll
    for (int kk = 0; kk < 4; kk++) {
        short8 ahi[4], alo[4];
#pragma unroll
        for (int q = 0; q < 4; q++) {
            const u16* p = arow + q * 128 + kk * 32;
            u32x4v xx = ntload((const u32x4v*)p);   // 8 fp16
#pragma unroll
            for (int j = 0; j < 4; j++) {
                u32 word = xx[j];
                float x0 = h2f(word & 0xffffu);
                float x1 = h2f(word >> 16);
                u16 h0 = f2bf(x0);
                ahi[q][2 * j]     = (short)h0;
                alo[q][2 * j]     = (short)f2bf(x0 - bf2f(h0));
                u16 h1 = f2bf(x1);
                ahi[q][2 * j + 1] = (short)h1;
                alo[q][2 * j + 1] = (short)f2bf(x1 - bf2f(h1));
            }
        }
#pragma unroll
        for (int jt = 0; jt < 4; jt++) {
            int bidx = (kk * 4 + jt) * 64 + lane;
            short8 wh_s = bsh[bidx];
            short8 wl_s = bsl[bidx];
            short8 wh_v = bvh[bidx];
            short8 wl_v = bvl[bidx];
            acc[0][jt] = mfma16(ahi[0], wh_s, acc[0][jt]);
            acc[0][jt] = mfma16(alo[0], wh_s, acc[0][jt]);
            acc[0][jt] = mfma16(ahi[0], wl_s, acc[0][jt]);
#pragma unroll
            for (int q = 1; q < 4; q++) {
                acc[q][jt] = mfma16(ahi[q], wh_v, acc[q][jt]);
                acc[q][jt] = mfma16(alo[q], wh_v, acc[q][jt]);
                acc[q][jt] = mfma16(ahi[q], wl_v, acc[q][jt]);
            }
        }
    }

#pragma unroll
    for (int r = 0; r < 4; r++) {
        int n = nb + hi * 4 + r;
        if (n < N_NODES) {
#pragma unroll
            for (int jt = 0; jt < 4; jt++) {
                int d = jt * 16 + lo16;
                f32x4 o;
                o.x = acc[0][jt][r] * 0.0625f;
                o.y = acc[1][jt][r] * 0.0625f;
                o.z = acc[2][jt][r] * 0.0625f;
                o.w = acc[3][jt][r] * 0.0625f;
                ntstore((f32x4*)(out + (size_t)n * 256 + d * 4), o);
            }
        }
    }
}

extern "C" void kernel_launch(void* const* d_in, const int* in_sizes, int n_in,
                              void* d_out, int out_size, void* d_ws, size_t ws_size,
                              hipStream_t stream) {
    (void)in_sizes; (void)n_in; (void)out_size; (void)ws_size;
    const float* node_feats = (const float*)d_in[0];
    const float* edge_attrs = (const float*)d_in[1];
    const float* edge_feats = (const float*)d_in[2];
    const float* lengths    = (const float*)d_in[3];
    const int*   edge_index = (const int*)d_in[4];
    const float* Wsc  = (const float*)d_in[5];
    const float* Wup0 = (const float*)d_in[6];
    const float* Wup1 = (const float*)d_in[7];
    const float* W1   = (const float*)d_in[8];
    const float* b1   = (const float*)d_in[9];
    const float* W2   = (const float*)d_in[10];
    const float* b2   = (const float*)d_in[11];
    const float* W3   = (const float*)d_in[12];
    const float* Ws   = (const float*)d_in[13];
    const float* Wv   = (const float*)d_in[14];

    char* ws = (char*)d_ws;
    u16*   ns_bf  = (u16*)(ws + OFF_NSBF);
    u16*   svh    = (u16*)(ws + OFF_SV);
    u16*   m_gh   = (u16*)(ws + OFF_MG);
    u16*   twg    = (u16*)(ws + OFF_TW);
    u16*   W1f    = (u16*)(ws + OFF_W1F);
    u16*   W2f    = (u16*)(ws + OFF_W2F);
    u16*   W3f    = (u16*)(ws + OFF_W3F);
    u16*   WNF    = (u16*)(ws + OFF_WNF);
    int*   cnt    = (int*)(ws + OFF_CNT);
    int*   offs   = (int*)(ws + OFF_OFFS);
    int*   cursor = (int*)(ws + OFF_CUR);
    u16*   WSF    = (u16*)(ws + OFF_WSF);
    int*   ssort  = (int*)(ws + OFF_SS);
    int*   rsort  = (int*)(ws + OFF_RS);
    float* easort = (float*)(ws + OFF_EA);
    u16*   efsort = (u16*)(ws + OFF_EF);
    u16*   lsort  = (u16*)(ws + OFF_LEN);
    float* out    = (float*)d_out;

    (void)hipMemsetAsync(cnt, 0, N_NODES * sizeof(int), stream);
    prep_all_kernel<<<29, 256, 0, stream>>>(W1, W2, W3, Wsc, Wup0, Wup1, Ws, Wv,
                                            W1f, W2f, W3f, WNF, WSF);
    node_prep_kernel<<<(N_NODES + 63) / 64, 256, 0, stream>>>(node_feats, WNF, ns_bf, svh);
    hist_kernel<<<N_EDGES / 256, 256, 0, stream>>>(edge_index, cnt);
    scan_kernel<<<1, 1024, 0, stream>>>(cnt, offs, cursor);
    scatter_kernel<<<N_EDGES / 256, 256, 0, stream>>>(edge_index, edge_attrs, edge_feats,
                                                      lengths, cursor,
                                                      ssort, rsort, easort, efsort, lsort);

    mlp_kernel<<<N_EDGES / 64, 256, 0, stream>>>(ns_bf, W1f, W2f, W3f, b1, b2,
                                                 ssort, rsort, efsort, lsort, twg);
    seg_kernel<<<N_NODES / 4, 256, 0, stream>>>(svh, easort, ssort,
                                                offs, twg, m_gh);
    out_kernel<<<(N_NODES + 63) / 64, 256, 0, stream>>>(m_gh, WSF, out);
}